// Round 3
// baseline (1352.052 us; speedup 1.0000x reference)
//
#include <hip/hip_runtime.h>
#include <hip/hip_bf16.h>

#define B   2
#define NN_ 5000
#define NE_ 160000
#define F   128
#define HID 128
#define ED  16

typedef __bf16 bf16x8 __attribute__((ext_vector_type(8)));
typedef __bf16 bf16x4 __attribute__((ext_vector_type(4)));
typedef float  f32x4  __attribute__((ext_vector_type(4)));

#define MS  136     // edge buf row stride (17 16B-units, odd -> conflict-free b128)
#define PS  40      // xs32 row stride
#define EDG 64      // edges per chunk
#define ZS  264     // node z row stride bf16
#define HS  136     // node h1 row stride
#define NPB2 32     // nodes per block (node phase)
#define GRID_BLKS 768      // 3 blocks/CU x 256 CU, guaranteed by __launch_bounds__(256,3)
#define NTHR (GRID_BLKS*256)
#define NCHUNK 5000        // (NE_/EDG)*B

// Manual grid barrier (sense/generation, agent-scope atomics). Safe because all
// GRID_BLKS blocks are co-resident by construction (LDS 37376B -> 4/CU cap;
// launch_bounds(256,3) -> VGPR cap for 3/CU; 768 = 3*256).
__device__ __forceinline__ void gridbar(int* cnt, int* gen) {
    __threadfence();                       // release: flush this XCD's L2 (all threads)
    __syncthreads();
    if (threadIdx.x == 0) {
        int g = __hip_atomic_load(gen, __ATOMIC_RELAXED, __HIP_MEMORY_SCOPE_AGENT);
        if (__hip_atomic_fetch_add(cnt, 1, __ATOMIC_ACQ_REL, __HIP_MEMORY_SCOPE_AGENT)
            == GRID_BLKS - 1) {
            __hip_atomic_store(cnt, 0, __ATOMIC_RELAXED, __HIP_MEMORY_SCOPE_AGENT);
            __hip_atomic_fetch_add(gen, 1, __ATOMIC_RELEASE, __HIP_MEMORY_SCOPE_AGENT);
        } else {
            while (__hip_atomic_load(gen, __ATOMIC_ACQUIRE, __HIP_MEMORY_SCOPE_AGENT) == g)
                __builtin_amdgcn_s_sleep(1);
        }
    }
    __syncthreads();
    __threadfence();                       // acquire: invalidate stale L1/L2
}

// One fused kernel:
//  P0 zero csr_cnt + agg | P1 histogram | P2 scan(blk0) + pr/pc GEMM(blk1..160) + pack(blk161+)
//  P3 scatter | P4 persistent edge phase (register prefetch, no spill) | P5 node phase
__global__ void __launch_bounds__(256, 3) fused_kernel(
    const float* __restrict__ h, const float* __restrict__ coord,
    const int* __restrict__ ei, const float* __restrict__ ea,
    const float* __restrict__ We1, const float* __restrict__ be1,
    const float* __restrict__ We2, const float* __restrict__ be2,
    const float* __restrict__ Wn1, const float* __restrict__ bn1,
    const float* __restrict__ Wn2, const float* __restrict__ bn2,
    const float* __restrict__ Wc1, const float* __restrict__ bc1,
    const float* __restrict__ Wc2,
    __bf16* __restrict__ pw1, __bf16* __restrict__ pw2,
    __bf16* __restrict__ pwc1, __bf16* __restrict__ pwc2,
    __bf16* __restrict__ pwn1, __bf16* __restrict__ pwn2,
    int* __restrict__ csr_cnt, int* __restrict__ csr_off, int* __restrict__ csr_pos,
    int* __restrict__ bucket, float* agg_h, float* agg_c,
    __bf16* __restrict__ pr, __bf16* __restrict__ pc,
    float* __restrict__ out_h, float* __restrict__ out_c,
    int* bar)
{
    __shared__ __align__(16) unsigned char smem[37376];
    int* bcnt = bar;
    int* bgen = bar + 1;
    const int t = threadIdx.x;
    const int blk = blockIdx.x;
    const int gtid = blk * 256 + t;

    // ================= P0: zero csr_cnt + agg_h/agg_c =================
    if (gtid < NN_) csr_cnt[gtid] = 0;
    {
        float4 z4 = {0.f, 0.f, 0.f, 0.f};
        float4* agg4 = (float4*)agg_h;           // agg_h + agg_c contiguous: 350000 float4
        for (int i = gtid; i < 350000; i += NTHR) agg4[i] = z4;
    }
    gridbar(bcnt, bgen);

    // ================= P1: histogram =================
    if (gtid < NE_) atomicAdd(&csr_cnt[ei[gtid]], 1);
    gridbar(bcnt, bgen);

    // ================= P2: scan | pr/pc GEMM | pack weights =================
    if (blk == 0) {
        int* part = (int*)smem;
        int sum = 0;
        #pragma unroll
        for (int j = 0; j < 20; j++) {
            int idx = t * 20 + j;
            if (idx < NN_) sum += csr_cnt[idx];
        }
        part[t] = sum;
        __syncthreads();
        for (int off = 1; off < 256; off <<= 1) {
            int v = (t >= off) ? part[t - off] : 0;
            __syncthreads();
            part[t] += v;
            __syncthreads();
        }
        int run = part[t] - sum;
        #pragma unroll
        for (int j = 0; j < 20; j++) {
            int idx = t * 20 + j;
            if (idx < NN_) { csr_off[idx] = run; csr_pos[idx] = run; run += csr_cnt[idx]; }
        }
        if (t == 0) csr_off[NN_] = NE_;
    } else if (blk <= 160) {
        // pr/pc GEMM: 160 blocks x 64-node tiles, raw We1 in fragment order, be1 fused into pr
        __bf16* hs = (__bf16*)smem;              // 64 * MS * 2 = 17408 B
        const int bp = blk - 1;                  // 0..159
        const int b  = bp / 80;
        const int n0 = (bp % 80) * 64;
        const int lane = t & 63, wave = t >> 6;
        const int quad = lane >> 4, c = lane & 15;
        #pragma unroll
        for (int it = 0; it < 8; it++) {
            int idx = it * 256 + t;              // 0..2047
            int node = idx >> 5, chh = idx & 31;
            int gn = n0 + node;
            float4 v = (gn < NN_) ? *(const float4*)&h[((size_t)b * NN_ + gn) * F + chh * 4]
                                  : (float4){0.f, 0.f, 0.f, 0.f};
            bf16x4 bv = {(__bf16)v.x, (__bf16)v.y, (__bf16)v.z, (__bf16)v.w};
            *(bf16x4*)&hs[node * MS + chh * 4] = bv;
        }
        __syncthreads();
        #pragma unroll
        for (int pass = 0; pass < 2; pass++) {
            const int nt = wave + pass * 4;      // 0..7
            f32x4 accr[4], accc[4];
            #pragma unroll
            for (int m = 0; m < 4; m++) { accr[m] = (f32x4){0,0,0,0}; accc[m] = (f32x4){0,0,0,0}; }
            for (int kt = 0; kt < 4; kt++) {
                bf16x8 wr, wc;
                #pragma unroll
                for (int jj = 0; jj < 8; jj++) {
                    int k = kt * 32 + quad * 8 + jj;
                    wr[jj] = (__bf16)We1[k * HID + nt * 16 + c];           // We1 rows 0..127
                    wc[jj] = (__bf16)We1[(k + 128) * HID + nt * 16 + c];   // rows 128..255
                }
                #pragma unroll
                for (int m = 0; m < 4; m++) {
                    bf16x8 x = *(const bf16x8*)&hs[(m * 16 + c) * MS + kt * 32 + quad * 8];
                    accr[m] = __builtin_amdgcn_mfma_f32_16x16x32_bf16(wr, x, accr[m], 0, 0, 0);
                    accc[m] = __builtin_amdgcn_mfma_f32_16x16x32_bf16(wc, x, accc[m], 0, 0, 0);
                }
            }
            float4 bb = *(const float4*)&be1[nt * 16 + quad * 4];
            #pragma unroll
            for (int m = 0; m < 4; m++) {
                int gn = n0 + m * 16 + c;
                if (gn < NN_) {
                    size_t base = ((size_t)b * NN_ + gn) * F + nt * 16 + quad * 4;
                    bf16x4 orr = {(__bf16)(accr[m][0] + bb.x), (__bf16)(accr[m][1] + bb.y),
                                  (__bf16)(accr[m][2] + bb.z), (__bf16)(accr[m][3] + bb.w)};
                    bf16x4 occ = {(__bf16)accc[m][0], (__bf16)accc[m][1],
                                  (__bf16)accc[m][2], (__bf16)accc[m][3]};
                    *(bf16x4*)&pr[base] = orr;
                    *(bf16x4*)&pc[base] = occ;
                }
            }
        }
    } else {
        // pack weights into MFMA fragment order
        for (int idx = (blk - 161) * 256 + t; idx < 120832; idx += (GRID_BLKS - 161) * 256) {
            const float* W; __bf16* P; int KT, Nr, local;
            if (idx < 36864)       { W = We1; P = pw1;  KT = 9; Nr = 128; local = idx; }
            else if (idx < 53248)  { W = We2; P = pw2;  KT = 4; Nr = 128; local = idx - 36864; }
            else if (idx < 69632)  { W = Wc1; P = pwc1; KT = 4; Nr = 128; local = idx - 53248; }
            else if (idx < 71680)  { W = Wc2; P = pwc2; KT = 4; Nr = 4;   local = idx - 69632; }
            else if (idx < 104448) { W = Wn1; P = pwn1; KT = 8; Nr = 128; local = idx - 71680; }
            else                   { W = Wn2; P = pwn2; KT = 4; Nr = 128; local = idx - 104448; }
            int j = local & 7, lane = (local >> 3) & 63, rest = local >> 9;
            int kt = rest % KT, nt2 = rest / KT;
            int k = kt * 32 + (lane >> 4) * 8 + j;
            int n = nt2 * 16 + (lane & 15);
            float v = (n < Nr) ? W[k * Nr + n] : 0.f;
            P[local] = (__bf16)v;
        }
    }
    gridbar(bcnt, bgen);

    // ================= P3: scatter =================
    if (gtid < NE_) {
        int p = atomicAdd(&csr_pos[ei[gtid]], 1);
        bucket[p] = gtid;
    }
    gridbar(bcnt, bgen);

    // ================= P4: edge phase (contiguous chunk ranges, named-reg prefetch) =====
    {
        __bf16* buf1 = (__bf16*)smem;                       // 17408 B  presum -> h1 -> h2
        __bf16* buf2 = (__bf16*)(smem + 17408);             // 17408 B  xs32 -> ef
        __bf16 (*cds)[12] = (__bf16(*)[12])(smem + 34816);  // 1536 B
        int* rs    = (int*)(smem + 36352);
        int* rsN   = (int*)(smem + 36608);
        int* csN   = (int*)(smem + 36864);
        int* eidsN = (int*)(smem + 37120);                  // ends 37376

        const int lane = t & 63, wave = t >> 6;
        const int quad = lane >> 4, c = lane & 15;
        const int e4 = t >> 2, j4 = t & 3;                  // radial: 4 threads per edge
        const int eB = t >> 4, chB = t & 15;                // presum: edges eB,16+eB,32+eB,48+eB

        const bf16x8* pw1v  = (const bf16x8*)pw1;
        const bf16x8* pw2v  = (const bf16x8*)pw2;
        const bf16x8* pwc1v = (const bf16x8*)pwc1;
        const bf16x8* pwc2v = (const bf16x8*)pwc2;

        bf16x8 pcA, pcB, pcC, pcD;                          // named regs: no spill
        float crN0, crN1, crN2, ccN0, ccN1, ccN2;
        float4 eaNv;

        // contiguous chunk range per block (pr locality, serialized same-node atomics)
        const int c0 = (int)(((long long)blk * NCHUNK) / GRID_BLKS);
        const int c1 = (int)(((long long)(blk + 1) * NCHUNK) / GRID_BLKS);

        {   // cold meta for chunk c0
            const int bC = (c0 >= 2500) ? 1 : 0;
            const int p0 = (c0 - bC * 2500) * EDG;
            if (t < EDG) {
                int me = bucket[p0 + t];
                rsN[t] = ei[me]; csN[t] = ei[NE_ + me]; eidsN[t] = me;
            }
        }
        __syncthreads();
        {   // cold prefetch (pc random gather + coord + ea)
            const int bC = (c0 >= 2500) ? 1 : 0;
            const __bf16* pcb = pc + (size_t)bC * NN_ * F;
            pcA = *(const bf16x8*)(pcb + (size_t)csN[eB]      * F + chB * 8);
            pcB = *(const bf16x8*)(pcb + (size_t)csN[16 + eB] * F + chB * 8);
            pcC = *(const bf16x8*)(pcb + (size_t)csN[32 + eB] * F + chB * 8);
            pcD = *(const bf16x8*)(pcb + (size_t)csN[48 + eB] * F + chB * 8);
            const float* crp = coord + ((size_t)bC * NN_ + rsN[e4]) * 12 + j4 * 3;
            const float* ccp = coord + ((size_t)bC * NN_ + csN[e4]) * 12 + j4 * 3;
            crN0 = crp[0]; crN1 = crp[1]; crN2 = crp[2];
            ccN0 = ccp[0]; ccN1 = ccp[1]; ccN2 = ccp[2];
            eaNv = *(const float4*)(ea + (size_t)eidsN[e4] * ED + j4 * 4);
        }

        for (int cid = c0; cid < c1; cid++) {
            const int bCur = (cid >= 2500) ? 1 : 0;
            const int nid  = (cid + 1 < c1) ? (cid + 1) : cid;   // clamp: last iter re-prefetches self
            const int bN   = (nid >= 2500) ? 1 : 0;
            const int p0n  = (nid - bN * 2500) * EDG;

            // ---- S: presum flush (pr synchronous: few distinct sorted rows, L2-hot) ----
            {
                const __bf16* prb = pr + (size_t)bCur * NN_ * F;
                bf16x8 a0 = *(const bf16x8*)(prb + (size_t)rsN[eB]      * F + chB * 8);
                bf16x8 a1 = *(const bf16x8*)(prb + (size_t)rsN[16 + eB] * F + chB * 8);
                bf16x8 a2 = *(const bf16x8*)(prb + (size_t)rsN[32 + eB] * F + chB * 8);
                bf16x8 a3 = *(const bf16x8*)(prb + (size_t)rsN[48 + eB] * F + chB * 8);
                bf16x8 o0, o1, o2, o3;
                #pragma unroll
                for (int j = 0; j < 8; j++) {
                    o0[j] = (__bf16)((float)a0[j] + (float)pcA[j]);
                    o1[j] = (__bf16)((float)a1[j] + (float)pcB[j]);
                    o2[j] = (__bf16)((float)a2[j] + (float)pcC[j]);
                    o3[j] = (__bf16)((float)a3[j] + (float)pcD[j]);
                }
                *(bf16x8*)&buf1[(eB)      * MS + chB * 8] = o0;
                *(bf16x8*)&buf1[(16 + eB) * MS + chB * 8] = o1;
                *(bf16x8*)&buf1[(32 + eB) * MS + chB * 8] = o2;
                *(bf16x8*)&buf1[(48 + eB) * MS + chB * 8] = o3;
            }
            {   // radial from prefetched coords, 4 threads/edge
                float cd0 = crN0 - ccN0, cd1 = crN1 - ccN1, cd2 = crN2 - ccN2;
                cds[e4][j4 * 3 + 0] = (__bf16)cd0;
                cds[e4][j4 * 3 + 1] = (__bf16)cd1;
                cds[e4][j4 * 3 + 2] = (__bf16)cd2;
                float px[4], ss = 0.f;
                #pragma unroll
                for (int k = 0; k < 4; k++) {
                    int sl = (lane & ~3) | k;
                    float bx = __shfl(cd0, sl, 64);
                    float by = __shfl(cd1, sl, 64);
                    float bz = __shfl(cd2, sl, 64);
                    px[k] = cd0 * bx + cd1 * by + cd2 * bz;
                    ss += px[k] * px[k];
                }
                ss += __shfl_xor(ss, 1, 64);
                ss += __shfl_xor(ss, 2, 64);
                float inv = 1.0f / fmaxf(sqrtf(ss), 1e-12f);
                bf16x4 xp = {(__bf16)(px[0] * inv), (__bf16)(px[1] * inv),
                             (__bf16)(px[2] * inv), (__bf16)(px[3] * inv)};
                *(bf16x4*)&buf2[e4 * PS + j4 * 4] = xp;
                bf16x4 bea = {(__bf16)eaNv.x, (__bf16)eaNv.y, (__bf16)eaNv.z, (__bf16)eaNv.w};
                *(bf16x4*)&buf2[e4 * PS + 16 + j4 * 4] = bea;
            }
            if (t < EDG) rs[t] = rsN[t];
            __syncthreads();

            // ---- issue next-chunk metadata (chain hides under e1) ----
            int mr = 0, mc = 0, me = 0;
            if (t < EDG) {
                me = bucket[p0n + t];
                mr = ei[me];
                mc = ei[NE_ + me];
            }

            // ===== e1: K=32 (kt=8 tile of pw1) + presum =====
            f32x4 acc1[4][2];
            #pragma unroll
            for (int m = 0; m < 4; m++)
                #pragma unroll
                for (int n = 0; n < 2; n++) acc1[m][n] = (f32x4){0,0,0,0};
            {
                bf16x8 x1[4];
                #pragma unroll
                for (int m = 0; m < 4; m++)
                    x1[m] = *(const bf16x8*)&buf2[(m * 16 + c) * PS + quad * 8];
                #pragma unroll
                for (int n = 0; n < 2; n++) {
                    bf16x8 w = pw1v[((2 * wave + n) * 9 + 8) * 64 + lane];
                    #pragma unroll
                    for (int m = 0; m < 4; m++)
                        acc1[m][n] = __builtin_amdgcn_mfma_f32_16x16x32_bf16(w, x1[m], acc1[m][n], 0, 0, 0);
                }
            }
            #pragma unroll
            for (int n = 0; n < 2; n++) {
                int nt = 2 * wave + n;
                #pragma unroll
                for (int m = 0; m < 4; m++) {
                    int row = m * 16 + c;
                    bf16x4 pp = *(const bf16x4*)&buf1[row * MS + nt * 16 + quad * 4];
                    bf16x4 o = { (__bf16)fmaxf(acc1[m][n][0] + (float)pp[0], 0.f),
                                 (__bf16)fmaxf(acc1[m][n][1] + (float)pp[1], 0.f),
                                 (__bf16)fmaxf(acc1[m][n][2] + (float)pp[2], 0.f),
                                 (__bf16)fmaxf(acc1[m][n][3] + (float)pp[3], 0.f) };
                    *(bf16x4*)&buf1[row * MS + nt * 16 + quad * 4] = o;
                }
            }
            if (t < EDG) { rsN[t] = mr; csN[t] = mc; eidsN[t] = me; }
            __syncthreads();

            // ---- issue next-chunk prefetch (hides under e2/c1/c2/seg-reduce) ----
            {
                const __bf16* pcb = pc + (size_t)bN * NN_ * F;
                pcA = *(const bf16x8*)(pcb + (size_t)csN[eB]      * F + chB * 8);
                pcB = *(const bf16x8*)(pcb + (size_t)csN[16 + eB] * F + chB * 8);
                pcC = *(const bf16x8*)(pcb + (size_t)csN[32 + eB] * F + chB * 8);
                pcD = *(const bf16x8*)(pcb + (size_t)csN[48 + eB] * F + chB * 8);
                const float* crp = coord + ((size_t)bN * NN_ + rsN[e4]) * 12 + j4 * 3;
                const float* ccp = coord + ((size_t)bN * NN_ + csN[e4]) * 12 + j4 * 3;
                crN0 = crp[0]; crN1 = crp[1]; crN2 = crp[2];
                ccN0 = ccp[0]; ccN1 = ccp[1]; ccN2 = ccp[2];
                eaNv = *(const float4*)(ea + (size_t)eidsN[e4] * ED + j4 * 4);
            }

            // ===== e2: h1 @ We2 -> ef (buf2, stride MS) =====
            f32x4 acc2[4][2];
            #pragma unroll
            for (int m = 0; m < 4; m++)
                #pragma unroll
                for (int n = 0; n < 2; n++) acc2[m][n] = (f32x4){0,0,0,0};
            for (int kt = 0; kt < 4; kt++) {
                bf16x8 x[4];
                #pragma unroll
                for (int m = 0; m < 4; m++)
                    x[m] = *(const bf16x8*)&buf1[(m * 16 + c) * MS + kt * 32 + quad * 8];
                #pragma unroll
                for (int n = 0; n < 2; n++) {
                    bf16x8 w = pw2v[((2 * wave + n) * 4 + kt) * 64 + lane];
                    #pragma unroll
                    for (int m = 0; m < 4; m++)
                        acc2[m][n] = __builtin_amdgcn_mfma_f32_16x16x32_bf16(w, x[m], acc2[m][n], 0, 0, 0);
                }
            }
            #pragma unroll
            for (int n = 0; n < 2; n++) {
                int nt = 2 * wave + n;
                float4 bb = *(const float4*)&be2[nt * 16 + quad * 4];
                #pragma unroll
                for (int m = 0; m < 4; m++) {
                    int row = m * 16 + c;
                    bf16x4 o = { (__bf16)fmaxf(acc2[m][n][0] + bb.x, 0.f),
                                 (__bf16)fmaxf(acc2[m][n][1] + bb.y, 0.f),
                                 (__bf16)fmaxf(acc2[m][n][2] + bb.z, 0.f),
                                 (__bf16)fmaxf(acc2[m][n][3] + bb.w, 0.f) };
                    *(bf16x4*)&buf2[row * MS + nt * 16 + quad * 4] = o;
                }
            }
            __syncthreads();   // buf2 (ef) stable from here on

            // ===== c1: ef @ Wc1 -> buf1 =====
            f32x4 acc3[4][2];
            #pragma unroll
            for (int m = 0; m < 4; m++)
                #pragma unroll
                for (int n = 0; n < 2; n++) acc3[m][n] = (f32x4){0,0,0,0};
            for (int kt = 0; kt < 4; kt++) {
                bf16x8 x[4];
                #pragma unroll
                for (int m = 0; m < 4; m++)
                    x[m] = *(const bf16x8*)&buf2[(m * 16 + c) * MS + kt * 32 + quad * 8];
                #pragma unroll
                for (int n = 0; n < 2; n++) {
                    bf16x8 w = pwc1v[((2 * wave + n) * 4 + kt) * 64 + lane];
                    #pragma unroll
                    for (int m = 0; m < 4; m++)
                        acc3[m][n] = __builtin_amdgcn_mfma_f32_16x16x32_bf16(w, x[m], acc3[m][n], 0, 0, 0);
                }
            }
            #pragma unroll
            for (int n = 0; n < 2; n++) {
                int nt = 2 * wave + n;
                float4 bb = *(const float4*)&bc1[nt * 16 + quad * 4];
                #pragma unroll
                for (int m = 0; m < 4; m++) {
                    int row = m * 16 + c;
                    bf16x4 o = { (__bf16)fmaxf(acc3[m][n][0] + bb.x, 0.f),
                                 (__bf16)fmaxf(acc3[m][n][1] + bb.y, 0.f),
                                 (__bf16)fmaxf(acc3[m][n][2] + bb.z, 0.f),
                                 (__bf16)fmaxf(acc3[m][n][3] + bb.w, 0.f) };
                    *(bf16x4*)&buf1[row * MS + nt * 16 + quad * 4] = o;
                }
            }
            __syncthreads();

            // ===== c2: wave owns m-tile = wave =====
            f32x4 accw = (f32x4){0,0,0,0};
            for (int kt = 0; kt < 4; kt++) {
                bf16x8 x = *(const bf16x8*)&buf1[(wave * 16 + c) * MS + kt * 32 + quad * 8];
                accw = __builtin_amdgcn_mfma_f32_16x16x32_bf16(pwc2v[kt * 64 + lane], x, accw, 0, 0, 0);
            }
            if (quad == 0) {
                int e = wave * 16 + c;
                #pragma unroll
                for (int j = 0; j < 12; j++)
                    cds[e][j] = (__bf16)((float)cds[e][j] * accw[j / 3]);
            }

            // ===== agg_h seg-reduce (reads only buf2; overlaps other waves' c2) =====
            {
                float* aggh_b = agg_h + (size_t)bCur * NN_ * HID;
                const int col = t & 127, seg = t >> 7;
                float run = 0.f;
                int cur = rs[seg * 32];
                for (int e = seg * 32; e < seg * 32 + 32; e++) {
                    int r = rs[e];
                    float v = (float)buf2[e * MS + col];
                    if (r != cur) {
                        atomicAdd(&aggh_b[(size_t)cur * HID + col], run);
                        run = 0.f; cur = r;
                    }
                    run += v;
                }
                atomicAdd(&aggh_b[(size_t)cur * HID + col], run);
            }
            __syncthreads();   // cds updates visible

            if (t < 24) {
                float* aggc_b = agg_c + (size_t)bCur * NN_ * 12;
                const int j = t % 12, q = t / 12;
                float run = 0.f;
                int cur = rs[q * 32];
                for (int e = q * 32; e < q * 32 + 32; e++) {
                    int r = rs[e];
                    float v = (float)cds[e][j];
                    if (r != cur) {
                        atomicAdd(&aggc_b[(size_t)cur * 12 + j], run);
                        run = 0.f; cur = r;
                    }
                    run += v;
                }
                atomicAdd(&aggc_b[(size_t)cur * 12 + j], run);
            }
            __syncthreads();   // protect LDS before next chunk's S-write
        }
    }
    gridbar(bcnt, bgen);

    // ================= P5: node phase =================
    if (blk < 314) {
        __bf16* zs  = (__bf16*)smem;                 // 16896 B, reused as os (fp32, stride 132)
        __bf16* h1s = (__bf16*)(smem + 16896);       // 8704 B
        const int b  = blk / 157;
        const int n0 = (blk % 157) * NPB2;
        const int lane = t & 63, wave = t >> 6;
        const int quad = lane >> 4, c = lane & 15;

        #pragma unroll
        for (int it = 0; it < 8; it++) {
            int idx = it * 256 + t;              // 0..2047
            int node = idx >> 6, ch = idx & 63;  // ch 0..31 = h, 32..63 = agg_h
            int gn = n0 + node;
            float4 v = (float4){0.f, 0.f, 0.f, 0.f};
            if (gn < NN_) {
                const float* src = (ch < 32) ? &h[((size_t)b * NN_ + gn) * F + ch * 4]
                                             : &agg_h[((size_t)b * NN_ + gn) * HID + (ch - 32) * 4];
                v = *(const float4*)src;
            }
            bf16x4 bv = {(__bf16)v.x, (__bf16)v.y, (__bf16)v.z, (__bf16)v.w};
            *(bf16x4*)&zs[node * ZS + ch * 4] = bv;
        }
        __syncthreads();

        const bf16x8* w1v = (const bf16x8*)pwn1;
        const bf16x8* w2v = (const bf16x8*)pwn2;
        f32x4 a1[2][2];
        #pragma unroll
        for (int m = 0; m < 2; m++)
            #pragma unroll
            for (int n = 0; n < 2; n++) a1[m][n] = (f32x4){0,0,0,0};
        for (int kt = 0; kt < 8; kt++) {
            bf16x8 x[2];
            #pragma unroll
            for (int m = 0; m < 2; m++)
                x[m] = *(const bf16x8*)&zs[(m * 16 + c) * ZS + kt * 32 + quad * 8];
            #pragma unroll
            for (int n = 0; n < 2; n++) {
                bf16x8 w = w1v[((2 * wave + n) * 8 + kt) * 64 + lane];
                #pragma unroll
                for (int m = 0; m < 2; m++)
                    a1[m][n] = __builtin_amdgcn_mfma_f32_16x16x32_bf16(w, x[m], a1[m][n], 0, 0, 0);
            }
        }
        __syncthreads();
        #pragma unroll
        for (int n = 0; n < 2; n++) {
            int nt = 2 * wave + n;
            float4 bb = *(const float4*)&bn1[nt * 16 + quad * 4];
            #pragma unroll
            for (int m = 0; m < 2; m++) {
                bf16x4 o = { (__bf16)fmaxf(a1[m][n][0] + bb.x, 0.f),
                             (__bf16)fmaxf(a1[m][n][1] + bb.y, 0.f),
                             (__bf16)fmaxf(a1[m][n][2] + bb.z, 0.f),
                             (__bf16)fmaxf(a1[m][n][3] + bb.w, 0.f) };
                *(bf16x4*)&h1s[(m * 16 + c) * HS + nt * 16 + quad * 4] = o;
            }
        }
        __syncthreads();

        f32x4 a2[2][2];
        #pragma unroll
        for (int m = 0; m < 2; m++)
            #pragma unroll
            for (int n = 0; n < 2; n++) a2[m][n] = (f32x4){0,0,0,0};
        for (int kt = 0; kt < 4; kt++) {
            bf16x8 x[2];
            #pragma unroll
            for (int m = 0; m < 2; m++)
                x[m] = *(const bf16x8*)&h1s[(m * 16 + c) * HS + kt * 32 + quad * 8];
            #pragma unroll
            for (int n = 0; n < 2; n++) {
                bf16x8 w = w2v[((2 * wave + n) * 4 + kt) * 64 + lane];
                #pragma unroll
                for (int m = 0; m < 2; m++)
                    a2[m][n] = __builtin_amdgcn_mfma_f32_16x16x32_bf16(w, x[m], a2[m][n], 0, 0, 0);
            }
        }
        float* os = (float*)zs;   // stride 132 floats
        #pragma unroll
        for (int n = 0; n < 2; n++) {
            int nt = 2 * wave + n;
            float4 bb = *(const float4*)&bn2[nt * 16 + quad * 4];
            #pragma unroll
            for (int m = 0; m < 2; m++) {
                f32x4 o = { a2[m][n][0] + bb.x, a2[m][n][1] + bb.y,
                            a2[m][n][2] + bb.z, a2[m][n][3] + bb.w };
                *(f32x4*)&os[(m * 16 + c) * 132 + nt * 16 + quad * 4] = o;
            }
        }
        __syncthreads();

        #pragma unroll
        for (int it = 0; it < 4; it++) {
            int idx = it * 256 + t;              // 0..1023
            int node = idx >> 5, ch = idx & 31;
            int gn = n0 + node;
            if (gn < NN_) {
                size_t gb = ((size_t)b * NN_ + gn) * F + ch * 4;
                float4 hres = *(const float4*)&h[gb];
                float4 acc = *(const float4*)&os[node * 132 + ch * 4];
                float4 o = { hres.x + acc.x, hres.y + acc.y, hres.z + acc.z, hres.w + acc.w };
                *(float4*)&out_h[gb] = o;
            }
        }
        for (int idx = t; idx < NPB2 * 12; idx += 256) {
            int node = idx / 12, j = idx % 12;
            int gn = n0 + node;
            if (gn < NN_) {
                float deg = (float)(csr_off[gn + 1] - csr_off[gn]);
                size_t ci = ((size_t)b * NN_ + gn) * 12 + j;
                out_c[ci] = coord[ci] + agg_c[ci] / fmaxf(deg, 1.0f);
            }
        }
    }
}

extern "C" void kernel_launch(void* const* d_in, const int* in_sizes, int n_in,
                              void* d_out, int out_size, void* d_ws, size_t ws_size,
                              hipStream_t stream) {
    const float* h     = (const float*)d_in[0];
    const float* coord = (const float*)d_in[1];
    const int*   ei    = (const int*)d_in[2];
    const float* ea    = (const float*)d_in[3];
    const float* We1   = (const float*)d_in[4];
    const float* be1   = (const float*)d_in[5];
    const float* We2   = (const float*)d_in[6];
    const float* be2   = (const float*)d_in[7];
    const float* Wn1   = (const float*)d_in[8];
    const float* bn1   = (const float*)d_in[9];
    const float* Wn2   = (const float*)d_in[10];
    const float* bn2   = (const float*)d_in[11];
    const float* Wc1   = (const float*)d_in[12];
    const float* bc1   = (const float*)d_in[13];
    const float* Wc2   = (const float*)d_in[14];

    float* out_h = (float*)d_out;                       // [B,N,F]
    float* out_c = out_h + (size_t)B * NN_ * F;         // [B,N,4,3]

    unsigned char* base = (unsigned char*)d_ws;
    __bf16* pw1  = (__bf16*)base;             // 36864 bf16
    __bf16* pw2  = pw1 + 36864;               // 16384
    __bf16* pwc1 = pw2 + 16384;               // 16384
    __bf16* pwc2 = pwc1 + 16384;              // 2048
    __bf16* pwn1 = pwc2 + 2048;               // 32768
    __bf16* pwn2 = pwn1 + 32768;              // 16384  -> 120832 elems = 241664 B
    unsigned char* dyn = base + 241664;

    int* csr_cnt = (int*)(dyn);               // 20000 B
    int* csr_off = (int*)(dyn + 20000);       // 20016 B
    int* csr_pos = (int*)(dyn + 40016);       // 20000 B
    int* bucket  = (int*)(dyn + 60016);       // 640000 B
    float* agg_h = (float*)(dyn + 700016);    // [B,N,HID]  5,120,000 B
    float* agg_c = agg_h + (size_t)B * NN_ * HID;            // [B,N,12] 480,000 B
    __bf16* pr   = (__bf16*)(agg_c + (size_t)B * NN_ * 12);  // 2,560,000 B
    __bf16* pc   = pr + (size_t)B * NN_ * F;                 // 2,560,000 B
    int* bar     = (int*)(dyn + 11420016);    // 8 B barrier state (cnt, gen)

    hipMemsetAsync(bar, 0, 8, stream);

    fused_kernel<<<GRID_BLKS, 256, 0, stream>>>(
        h, coord, ei, ea, We1, be1, We2, be2, Wn1, bn1, Wn2, bn2, Wc1, bc1, Wc2,
        pw1, pw2, pwc1, pwc2, pwn1, pwn2,
        csr_cnt, csr_off, csr_pos, bucket, agg_h, agg_c, pr, pc,
        out_h, out_c, bar);
}

// Round 4
// 835.779 us; speedup vs baseline: 1.6177x; 1.6177x over previous
//
#include <hip/hip_runtime.h>
#include <hip/hip_bf16.h>

#define B   2
#define NN_ 5000
#define NE_ 160000
#define F   128
#define HID 128
#define ED  16

typedef __bf16 bf16x8 __attribute__((ext_vector_type(8)));
typedef __bf16 bf16x4 __attribute__((ext_vector_type(4)));
typedef float  f32x4  __attribute__((ext_vector_type(4)));

#define MS  136     // edge buf row stride (17 16B-units, odd -> conflict-free b128)
#define PS  40      // xs32 row stride
#define EDG 64      // edges per chunk
#define ZS  264     // node z row stride bf16
#define HS  136     // node h1 row stride
#define NPB2 32     // nodes per block (node phase)
#define GRID_BLKS 768      // 3 blocks/CU x 256 CU, guaranteed co-resident
#define NTHR (GRID_BLKS*256)
#define NCHUNK 5000        // (NE_/EDG)*B
#define NGRP 24            // tree barrier: 24 groups x 32 blocks

// ---- tree grid barrier ----
// All polls are atomic RMWs (coherence-point ops; immune to stale non-coherent
// L2 reads). Counters are monotonic (epoch-relative compare, no reset races).
// Lines padded to 256B; <=31 pollers per line. Fences: thread0-only
// __threadfence() (wbl2+inv are cache-wide; producer stores reach L2 via the
// vmcnt(0) drain __syncthreads emits).
__device__ __forceinline__ int rmw_read(int* p) {
    return __hip_atomic_fetch_add(p, 0, __ATOMIC_ACQUIRE, __HIP_MEMORY_SCOPE_AGENT);
}
__device__ __forceinline__ void gridbar(int* bar, int epoch) {
    __syncthreads();                        // drains vmcnt/lgkmcnt for all waves
    if (threadIdx.x == 0) {
        __threadfence();                    // one wbl2+inv per block (release)
        const int blk = blockIdx.x;
        const int g = blk >> 5;             // 0..23
        int* gcnt    = bar + 128 + g * 64;
        int* ggen    = bar + 128 + NGRP * 64 + g * 64;
        int* rootcnt = bar;
        int* rootgen = bar + 64;
        int a = __hip_atomic_fetch_add(gcnt, 1, __ATOMIC_ACQ_REL, __HIP_MEMORY_SCOPE_AGENT);
        if (a == epoch * 32 + 31) {         // last of group
            int r = __hip_atomic_fetch_add(rootcnt, 1, __ATOMIC_ACQ_REL, __HIP_MEMORY_SCOPE_AGENT);
            if (r == epoch * NGRP + (NGRP - 1)) {
                __hip_atomic_fetch_add(rootgen, 1, __ATOMIC_RELEASE, __HIP_MEMORY_SCOPE_AGENT);
            } else {
                while (rmw_read(rootgen) <= epoch) __builtin_amdgcn_s_sleep(4);
            }
            __hip_atomic_fetch_add(ggen, 1, __ATOMIC_RELEASE, __HIP_MEMORY_SCOPE_AGENT);
        } else {
            while (rmw_read(ggen) <= epoch) __builtin_amdgcn_s_sleep(4);
        }
        __threadfence();                    // acquire: invalidate stale L1/L2
    }
    __syncthreads();
}

// One fused kernel (csr_cnt pre-zeroed by hipMemsetAsync):
//  P1 zero agg + histogram | P2 scan(blk0) + pr/pc GEMM(blk1..160) + pack(blk161+)
//  P3 scatter | P4 persistent edge phase | P5 node phase
__global__ void __launch_bounds__(256, 3) fused_kernel(
    const float* __restrict__ h, const float* __restrict__ coord,
    const int* __restrict__ ei, const float* __restrict__ ea,
    const float* __restrict__ We1, const float* __restrict__ be1,
    const float* __restrict__ We2, const float* __restrict__ be2,
    const float* __restrict__ Wn1, const float* __restrict__ bn1,
    const float* __restrict__ Wn2, const float* __restrict__ bn2,
    const float* __restrict__ Wc1, const float* __restrict__ bc1,
    const float* __restrict__ Wc2,
    __bf16* __restrict__ pw1, __bf16* __restrict__ pw2,
    __bf16* __restrict__ pwc1, __bf16* __restrict__ pwc2,
    __bf16* __restrict__ pwn1, __bf16* __restrict__ pwn2,
    int* __restrict__ csr_cnt, int* __restrict__ csr_off, int* __restrict__ csr_pos,
    int* __restrict__ bucket, float* agg_h, float* agg_c,
    __bf16* __restrict__ pr, __bf16* __restrict__ pc,
    float* __restrict__ out_h, float* __restrict__ out_c,
    int* bar)
{
    __shared__ __align__(16) unsigned char smem[37376];
    const int t = threadIdx.x;
    const int blk = blockIdx.x;
    const int gtid = blk * 256 + t;

    // ================= P1: zero agg + histogram =================
    {
        float4 z4 = {0.f, 0.f, 0.f, 0.f};
        float4* agg4 = (float4*)agg_h;           // agg_h + agg_c contiguous: 350000 float4
        for (int i = gtid; i < 350000; i += NTHR) agg4[i] = z4;
    }
    if (gtid < NE_) atomicAdd(&csr_cnt[ei[gtid]], 1);
    gridbar(bar, 0);

    // ================= P2: scan | pr/pc GEMM | pack weights =================
    if (blk == 0) {
        int* part = (int*)smem;
        int sum = 0;
        #pragma unroll
        for (int j = 0; j < 20; j++) {
            int idx = t * 20 + j;
            if (idx < NN_) sum += csr_cnt[idx];
        }
        part[t] = sum;
        __syncthreads();
        for (int off = 1; off < 256; off <<= 1) {
            int v = (t >= off) ? part[t - off] : 0;
            __syncthreads();
            part[t] += v;
            __syncthreads();
        }
        int run = part[t] - sum;
        #pragma unroll
        for (int j = 0; j < 20; j++) {
            int idx = t * 20 + j;
            if (idx < NN_) { csr_off[idx] = run; csr_pos[idx] = run; run += csr_cnt[idx]; }
        }
        if (t == 0) csr_off[NN_] = NE_;
    } else if (blk <= 160) {
        // pr/pc GEMM: 160 blocks x 64-node tiles, raw We1 in fragment order, be1 fused into pr
        __bf16* hs = (__bf16*)smem;              // 64 * MS * 2 = 17408 B
        const int bp = blk - 1;                  // 0..159
        const int b  = bp / 80;
        const int n0 = (bp % 80) * 64;
        const int lane = t & 63, wave = t >> 6;
        const int quad = lane >> 4, c = lane & 15;
        #pragma unroll
        for (int it = 0; it < 8; it++) {
            int idx = it * 256 + t;              // 0..2047
            int node = idx >> 5, chh = idx & 31;
            int gn = n0 + node;
            float4 v = (gn < NN_) ? *(const float4*)&h[((size_t)b * NN_ + gn) * F + chh * 4]
                                  : (float4){0.f, 0.f, 0.f, 0.f};
            bf16x4 bv = {(__bf16)v.x, (__bf16)v.y, (__bf16)v.z, (__bf16)v.w};
            *(bf16x4*)&hs[node * MS + chh * 4] = bv;
        }
        __syncthreads();
        #pragma unroll
        for (int pass = 0; pass < 2; pass++) {
            const int nt = wave + pass * 4;      // 0..7
            f32x4 accr[4], accc[4];
            #pragma unroll
            for (int m = 0; m < 4; m++) { accr[m] = (f32x4){0,0,0,0}; accc[m] = (f32x4){0,0,0,0}; }
            for (int kt = 0; kt < 4; kt++) {
                bf16x8 wr, wc;
                #pragma unroll
                for (int jj = 0; jj < 8; jj++) {
                    int k = kt * 32 + quad * 8 + jj;
                    wr[jj] = (__bf16)We1[k * HID + nt * 16 + c];           // We1 rows 0..127
                    wc[jj] = (__bf16)We1[(k + 128) * HID + nt * 16 + c];   // rows 128..255
                }
                #pragma unroll
                for (int m = 0; m < 4; m++) {
                    bf16x8 x = *(const bf16x8*)&hs[(m * 16 + c) * MS + kt * 32 + quad * 8];
                    accr[m] = __builtin_amdgcn_mfma_f32_16x16x32_bf16(wr, x, accr[m], 0, 0, 0);
                    accc[m] = __builtin_amdgcn_mfma_f32_16x16x32_bf16(wc, x, accc[m], 0, 0, 0);
                }
            }
            float4 bb = *(const float4*)&be1[nt * 16 + quad * 4];
            #pragma unroll
            for (int m = 0; m < 4; m++) {
                int gn = n0 + m * 16 + c;
                if (gn < NN_) {
                    size_t base = ((size_t)b * NN_ + gn) * F + nt * 16 + quad * 4;
                    bf16x4 orr = {(__bf16)(accr[m][0] + bb.x), (__bf16)(accr[m][1] + bb.y),
                                  (__bf16)(accr[m][2] + bb.z), (__bf16)(accr[m][3] + bb.w)};
                    bf16x4 occ = {(__bf16)accc[m][0], (__bf16)accc[m][1],
                                  (__bf16)accc[m][2], (__bf16)accc[m][3]};
                    *(bf16x4*)&pr[base] = orr;
                    *(bf16x4*)&pc[base] = occ;
                }
            }
        }
    } else {
        // pack weights into MFMA fragment order
        for (int idx = (blk - 161) * 256 + t; idx < 120832; idx += (GRID_BLKS - 161) * 256) {
            const float* W; __bf16* P; int KT, Nr, local;
            if (idx < 36864)       { W = We1; P = pw1;  KT = 9; Nr = 128; local = idx; }
            else if (idx < 53248)  { W = We2; P = pw2;  KT = 4; Nr = 128; local = idx - 36864; }
            else if (idx < 69632)  { W = Wc1; P = pwc1; KT = 4; Nr = 128; local = idx - 53248; }
            else if (idx < 71680)  { W = Wc2; P = pwc2; KT = 4; Nr = 4;   local = idx - 69632; }
            else if (idx < 104448) { W = Wn1; P = pwn1; KT = 8; Nr = 128; local = idx - 71680; }
            else                   { W = Wn2; P = pwn2; KT = 4; Nr = 128; local = idx - 104448; }
            int j = local & 7, lane = (local >> 3) & 63, rest = local >> 9;
            int kt = rest % KT, nt2 = rest / KT;
            int k = kt * 32 + (lane >> 4) * 8 + j;
            int n = nt2 * 16 + (lane & 15);
            float v = (n < Nr) ? W[k * Nr + n] : 0.f;
            P[local] = (__bf16)v;
        }
    }
    gridbar(bar, 1);

    // ================= P3: scatter =================
    if (gtid < NE_) {
        int p = atomicAdd(&csr_pos[ei[gtid]], 1);
        bucket[p] = gtid;
    }
    gridbar(bar, 2);

    // ================= P4: edge phase (contiguous chunk ranges, named-reg prefetch) =====
    {
        __bf16* buf1 = (__bf16*)smem;                       // 17408 B  presum -> h1 -> h2
        __bf16* buf2 = (__bf16*)(smem + 17408);             // 17408 B  xs32 -> ef
        __bf16 (*cds)[12] = (__bf16(*)[12])(smem + 34816);  // 1536 B
        int* rs    = (int*)(smem + 36352);
        int* rsN   = (int*)(smem + 36608);
        int* csN   = (int*)(smem + 36864);
        int* eidsN = (int*)(smem + 37120);                  // ends 37376

        const int lane = t & 63, wave = t >> 6;
        const int quad = lane >> 4, c = lane & 15;
        const int e4 = t >> 2, j4 = t & 3;                  // radial: 4 threads per edge
        const int eB = t >> 4, chB = t & 15;                // presum: edges eB,16+eB,32+eB,48+eB

        const bf16x8* pw1v  = (const bf16x8*)pw1;
        const bf16x8* pw2v  = (const bf16x8*)pw2;
        const bf16x8* pwc1v = (const bf16x8*)pwc1;
        const bf16x8* pwc2v = (const bf16x8*)pwc2;

        bf16x8 pcA, pcB, pcC, pcD;                          // named regs: no spill
        float crN0, crN1, crN2, ccN0, ccN1, ccN2;
        float4 eaNv;

        // contiguous chunk range per block (pr locality, serialized same-node atomics)
        const int c0 = (int)(((long long)blk * NCHUNK) / GRID_BLKS);
        const int c1 = (int)(((long long)(blk + 1) * NCHUNK) / GRID_BLKS);

        {   // cold meta for chunk c0
            const int bC = (c0 >= 2500) ? 1 : 0;
            const int p0 = (c0 - bC * 2500) * EDG;
            if (t < EDG) {
                int me = bucket[p0 + t];
                rsN[t] = ei[me]; csN[t] = ei[NE_ + me]; eidsN[t] = me;
            }
        }
        __syncthreads();
        {   // cold prefetch (pc random gather + coord + ea)
            const int bC = (c0 >= 2500) ? 1 : 0;
            const __bf16* pcb = pc + (size_t)bC * NN_ * F;
            pcA = *(const bf16x8*)(pcb + (size_t)csN[eB]      * F + chB * 8);
            pcB = *(const bf16x8*)(pcb + (size_t)csN[16 + eB] * F + chB * 8);
            pcC = *(const bf16x8*)(pcb + (size_t)csN[32 + eB] * F + chB * 8);
            pcD = *(const bf16x8*)(pcb + (size_t)csN[48 + eB] * F + chB * 8);
            const float* crp = coord + ((size_t)bC * NN_ + rsN[e4]) * 12 + j4 * 3;
            const float* ccp = coord + ((size_t)bC * NN_ + csN[e4]) * 12 + j4 * 3;
            crN0 = crp[0]; crN1 = crp[1]; crN2 = crp[2];
            ccN0 = ccp[0]; ccN1 = ccp[1]; ccN2 = ccp[2];
            eaNv = *(const float4*)(ea + (size_t)eidsN[e4] * ED + j4 * 4);
        }

        for (int cid = c0; cid < c1; cid++) {
            const int bCur = (cid >= 2500) ? 1 : 0;
            const int nid  = (cid + 1 < c1) ? (cid + 1) : cid;   // clamp: last iter re-prefetches self
            const int bN   = (nid >= 2500) ? 1 : 0;
            const int p0n  = (nid - bN * 2500) * EDG;

            // ---- S: presum flush (pr synchronous: few distinct sorted rows, L2-hot) ----
            {
                const __bf16* prb = pr + (size_t)bCur * NN_ * F;
                bf16x8 a0 = *(const bf16x8*)(prb + (size_t)rsN[eB]      * F + chB * 8);
                bf16x8 a1 = *(const bf16x8*)(prb + (size_t)rsN[16 + eB] * F + chB * 8);
                bf16x8 a2 = *(const bf16x8*)(prb + (size_t)rsN[32 + eB] * F + chB * 8);
                bf16x8 a3 = *(const bf16x8*)(prb + (size_t)rsN[48 + eB] * F + chB * 8);
                bf16x8 o0, o1, o2, o3;
                #pragma unroll
                for (int j = 0; j < 8; j++) {
                    o0[j] = (__bf16)((float)a0[j] + (float)pcA[j]);
                    o1[j] = (__bf16)((float)a1[j] + (float)pcB[j]);
                    o2[j] = (__bf16)((float)a2[j] + (float)pcC[j]);
                    o3[j] = (__bf16)((float)a3[j] + (float)pcD[j]);
                }
                *(bf16x8*)&buf1[(eB)      * MS + chB * 8] = o0;
                *(bf16x8*)&buf1[(16 + eB) * MS + chB * 8] = o1;
                *(bf16x8*)&buf1[(32 + eB) * MS + chB * 8] = o2;
                *(bf16x8*)&buf1[(48 + eB) * MS + chB * 8] = o3;
            }
            {   // radial from prefetched coords, 4 threads/edge
                float cd0 = crN0 - ccN0, cd1 = crN1 - ccN1, cd2 = crN2 - ccN2;
                cds[e4][j4 * 3 + 0] = (__bf16)cd0;
                cds[e4][j4 * 3 + 1] = (__bf16)cd1;
                cds[e4][j4 * 3 + 2] = (__bf16)cd2;
                float px[4], ss = 0.f;
                #pragma unroll
                for (int k = 0; k < 4; k++) {
                    int sl = (lane & ~3) | k;
                    float bx = __shfl(cd0, sl, 64);
                    float by = __shfl(cd1, sl, 64);
                    float bz = __shfl(cd2, sl, 64);
                    px[k] = cd0 * bx + cd1 * by + cd2 * bz;
                    ss += px[k] * px[k];
                }
                ss += __shfl_xor(ss, 1, 64);
                ss += __shfl_xor(ss, 2, 64);
                float inv = 1.0f / fmaxf(sqrtf(ss), 1e-12f);
                bf16x4 xp = {(__bf16)(px[0] * inv), (__bf16)(px[1] * inv),
                             (__bf16)(px[2] * inv), (__bf16)(px[3] * inv)};
                *(bf16x4*)&buf2[e4 * PS + j4 * 4] = xp;
                bf16x4 bea = {(__bf16)eaNv.x, (__bf16)eaNv.y, (__bf16)eaNv.z, (__bf16)eaNv.w};
                *(bf16x4*)&buf2[e4 * PS + 16 + j4 * 4] = bea;
            }
            if (t < EDG) rs[t] = rsN[t];
            __syncthreads();

            // ---- issue next-chunk metadata (chain hides under e1) ----
            int mr = 0, mc = 0, me = 0;
            if (t < EDG) {
                me = bucket[p0n + t];
                mr = ei[me];
                mc = ei[NE_ + me];
            }

            // ===== e1: K=32 (kt=8 tile of pw1) + presum =====
            f32x4 acc1[4][2];
            #pragma unroll
            for (int m = 0; m < 4; m++)
                #pragma unroll
                for (int n = 0; n < 2; n++) acc1[m][n] = (f32x4){0,0,0,0};
            {
                bf16x8 x1[4];
                #pragma unroll
                for (int m = 0; m < 4; m++)
                    x1[m] = *(const bf16x8*)&buf2[(m * 16 + c) * PS + quad * 8];
                #pragma unroll
                for (int n = 0; n < 2; n++) {
                    bf16x8 w = pw1v[((2 * wave + n) * 9 + 8) * 64 + lane];
                    #pragma unroll
                    for (int m = 0; m < 4; m++)
                        acc1[m][n] = __builtin_amdgcn_mfma_f32_16x16x32_bf16(w, x1[m], acc1[m][n], 0, 0, 0);
                }
            }
            #pragma unroll
            for (int n = 0; n < 2; n++) {
                int nt = 2 * wave + n;
                #pragma unroll
                for (int m = 0; m < 4; m++) {
                    int row = m * 16 + c;
                    bf16x4 pp = *(const bf16x4*)&buf1[row * MS + nt * 16 + quad * 4];
                    bf16x4 o = { (__bf16)fmaxf(acc1[m][n][0] + (float)pp[0], 0.f),
                                 (__bf16)fmaxf(acc1[m][n][1] + (float)pp[1], 0.f),
                                 (__bf16)fmaxf(acc1[m][n][2] + (float)pp[2], 0.f),
                                 (__bf16)fmaxf(acc1[m][n][3] + (float)pp[3], 0.f) };
                    *(bf16x4*)&buf1[row * MS + nt * 16 + quad * 4] = o;
                }
            }
            if (t < EDG) { rsN[t] = mr; csN[t] = mc; eidsN[t] = me; }
            __syncthreads();

            // ---- issue next-chunk prefetch (hides under e2/c1/c2/seg-reduce) ----
            {
                const __bf16* pcb = pc + (size_t)bN * NN_ * F;
                pcA = *(const bf16x8*)(pcb + (size_t)csN[eB]      * F + chB * 8);
                pcB = *(const bf16x8*)(pcb + (size_t)csN[16 + eB] * F + chB * 8);
                pcC = *(const bf16x8*)(pcb + (size_t)csN[32 + eB] * F + chB * 8);
                pcD = *(const bf16x8*)(pcb + (size_t)csN[48 + eB] * F + chB * 8);
                const float* crp = coord + ((size_t)bN * NN_ + rsN[e4]) * 12 + j4 * 3;
                const float* ccp = coord + ((size_t)bN * NN_ + csN[e4]) * 12 + j4 * 3;
                crN0 = crp[0]; crN1 = crp[1]; crN2 = crp[2];
                ccN0 = ccp[0]; ccN1 = ccp[1]; ccN2 = ccp[2];
                eaNv = *(const float4*)(ea + (size_t)eidsN[e4] * ED + j4 * 4);
            }

            // ===== e2: h1 @ We2 -> ef (buf2, stride MS) =====
            f32x4 acc2[4][2];
            #pragma unroll
            for (int m = 0; m < 4; m++)
                #pragma unroll
                for (int n = 0; n < 2; n++) acc2[m][n] = (f32x4){0,0,0,0};
            for (int kt = 0; kt < 4; kt++) {
                bf16x8 x[4];
                #pragma unroll
                for (int m = 0; m < 4; m++)
                    x[m] = *(const bf16x8*)&buf1[(m * 16 + c) * MS + kt * 32 + quad * 8];
                #pragma unroll
                for (int n = 0; n < 2; n++) {
                    bf16x8 w = pw2v[((2 * wave + n) * 4 + kt) * 64 + lane];
                    #pragma unroll
                    for (int m = 0; m < 4; m++)
                        acc2[m][n] = __builtin_amdgcn_mfma_f32_16x16x32_bf16(w, x[m], acc2[m][n], 0, 0, 0);
                }
            }
            #pragma unroll
            for (int n = 0; n < 2; n++) {
                int nt = 2 * wave + n;
                float4 bb = *(const float4*)&be2[nt * 16 + quad * 4];
                #pragma unroll
                for (int m = 0; m < 4; m++) {
                    int row = m * 16 + c;
                    bf16x4 o = { (__bf16)fmaxf(acc2[m][n][0] + bb.x, 0.f),
                                 (__bf16)fmaxf(acc2[m][n][1] + bb.y, 0.f),
                                 (__bf16)fmaxf(acc2[m][n][2] + bb.z, 0.f),
                                 (__bf16)fmaxf(acc2[m][n][3] + bb.w, 0.f) };
                    *(bf16x4*)&buf2[row * MS + nt * 16 + quad * 4] = o;
                }
            }
            __syncthreads();   // buf2 (ef) stable from here on

            // ===== c1: ef @ Wc1 -> buf1 =====
            f32x4 acc3[4][2];
            #pragma unroll
            for (int m = 0; m < 4; m++)
                #pragma unroll
                for (int n = 0; n < 2; n++) acc3[m][n] = (f32x4){0,0,0,0};
            for (int kt = 0; kt < 4; kt++) {
                bf16x8 x[4];
                #pragma unroll
                for (int m = 0; m < 4; m++)
                    x[m] = *(const bf16x8*)&buf2[(m * 16 + c) * MS + kt * 32 + quad * 8];
                #pragma unroll
                for (int n = 0; n < 2; n++) {
                    bf16x8 w = pwc1v[((2 * wave + n) * 4 + kt) * 64 + lane];
                    #pragma unroll
                    for (int m = 0; m < 4; m++)
                        acc3[m][n] = __builtin_amdgcn_mfma_f32_16x16x32_bf16(w, x[m], acc3[m][n], 0, 0, 0);
                }
            }
            #pragma unroll
            for (int n = 0; n < 2; n++) {
                int nt = 2 * wave + n;
                float4 bb = *(const float4*)&bc1[nt * 16 + quad * 4];
                #pragma unroll
                for (int m = 0; m < 4; m++) {
                    int row = m * 16 + c;
                    bf16x4 o = { (__bf16)fmaxf(acc3[m][n][0] + bb.x, 0.f),
                                 (__bf16)fmaxf(acc3[m][n][1] + bb.y, 0.f),
                                 (__bf16)fmaxf(acc3[m][n][2] + bb.z, 0.f),
                                 (__bf16)fmaxf(acc3[m][n][3] + bb.w, 0.f) };
                    *(bf16x4*)&buf1[row * MS + nt * 16 + quad * 4] = o;
                }
            }
            __syncthreads();

            // ===== c2: wave owns m-tile = wave =====
            f32x4 accw = (f32x4){0,0,0,0};
            for (int kt = 0; kt < 4; kt++) {
                bf16x8 x = *(const bf16x8*)&buf1[(wave * 16 + c) * MS + kt * 32 + quad * 8];
                accw = __builtin_amdgcn_mfma_f32_16x16x32_bf16(pwc2v[kt * 64 + lane], x, accw, 0, 0, 0);
            }
            if (quad == 0) {
                int e = wave * 16 + c;
                #pragma unroll
                for (int j = 0; j < 12; j++)
                    cds[e][j] = (__bf16)((float)cds[e][j] * accw[j / 3]);
            }

            // ===== agg_h seg-reduce (reads only buf2; overlaps other waves' c2) =====
            {
                float* aggh_b = agg_h + (size_t)bCur * NN_ * HID;
                const int col = t & 127, seg = t >> 7;
                float run = 0.f;
                int cur = rs[seg * 32];
                for (int e = seg * 32; e < seg * 32 + 32; e++) {
                    int r = rs[e];
                    float v = (float)buf2[e * MS + col];
                    if (r != cur) {
                        atomicAdd(&aggh_b[(size_t)cur * HID + col], run);
                        run = 0.f; cur = r;
                    }
                    run += v;
                }
                atomicAdd(&aggh_b[(size_t)cur * HID + col], run);
            }
            __syncthreads();   // cds updates visible

            if (t < 24) {
                float* aggc_b = agg_c + (size_t)bCur * NN_ * 12;
                const int j = t % 12, q = t / 12;
                float run = 0.f;
                int cur = rs[q * 32];
                for (int e = q * 32; e < q * 32 + 32; e++) {
                    int r = rs[e];
                    float v = (float)cds[e][j];
                    if (r != cur) {
                        atomicAdd(&aggc_b[(size_t)cur * 12 + j], run);
                        run = 0.f; cur = r;
                    }
                    run += v;
                }
                atomicAdd(&aggc_b[(size_t)cur * 12 + j], run);
            }
            __syncthreads();   // protect LDS before next chunk's S-write
        }
    }
    gridbar(bar, 3);

    // ================= P5: node phase =================
    if (blk < 314) {
        __bf16* zs  = (__bf16*)smem;                 // 16896 B, reused as os (fp32, stride 132)
        __bf16* h1s = (__bf16*)(smem + 16896);       // 8704 B
        const int b  = blk / 157;
        const int n0 = (blk % 157) * NPB2;
        const int lane = t & 63, wave = t >> 6;
        const int quad = lane >> 4, c = lane & 15;

        #pragma unroll
        for (int it = 0; it < 8; it++) {
            int idx = it * 256 + t;              // 0..2047
            int node = idx >> 6, ch = idx & 63;  // ch 0..31 = h, 32..63 = agg_h
            int gn = n0 + node;
            float4 v = (float4){0.f, 0.f, 0.f, 0.f};
            if (gn < NN_) {
                const float* src = (ch < 32) ? &h[((size_t)b * NN_ + gn) * F + ch * 4]
                                             : &agg_h[((size_t)b * NN_ + gn) * HID + (ch - 32) * 4];
                v = *(const float4*)src;
            }
            bf16x4 bv = {(__bf16)v.x, (__bf16)v.y, (__bf16)v.z, (__bf16)v.w};
            *(bf16x4*)&zs[node * ZS + ch * 4] = bv;
        }
        __syncthreads();

        const bf16x8* w1v = (const bf16x8*)pwn1;
        const bf16x8* w2v = (const bf16x8*)pwn2;
        f32x4 a1[2][2];
        #pragma unroll
        for (int m = 0; m < 2; m++)
            #pragma unroll
            for (int n = 0; n < 2; n++) a1[m][n] = (f32x4){0,0,0,0};
        for (int kt = 0; kt < 8; kt++) {
            bf16x8 x[2];
            #pragma unroll
            for (int m = 0; m < 2; m++)
                x[m] = *(const bf16x8*)&zs[(m * 16 + c) * ZS + kt * 32 + quad * 8];
            #pragma unroll
            for (int n = 0; n < 2; n++) {
                bf16x8 w = w1v[((2 * wave + n) * 8 + kt) * 64 + lane];
                #pragma unroll
                for (int m = 0; m < 2; m++)
                    a1[m][n] = __builtin_amdgcn_mfma_f32_16x16x32_bf16(w, x[m], a1[m][n], 0, 0, 0);
            }
        }
        __syncthreads();
        #pragma unroll
        for (int n = 0; n < 2; n++) {
            int nt = 2 * wave + n;
            float4 bb = *(const float4*)&bn1[nt * 16 + quad * 4];
            #pragma unroll
            for (int m = 0; m < 2; m++) {
                bf16x4 o = { (__bf16)fmaxf(a1[m][n][0] + bb.x, 0.f),
                             (__bf16)fmaxf(a1[m][n][1] + bb.y, 0.f),
                             (__bf16)fmaxf(a1[m][n][2] + bb.z, 0.f),
                             (__bf16)fmaxf(a1[m][n][3] + bb.w, 0.f) };
                *(bf16x4*)&h1s[(m * 16 + c) * HS + nt * 16 + quad * 4] = o;
            }
        }
        __syncthreads();

        f32x4 a2[2][2];
        #pragma unroll
        for (int m = 0; m < 2; m++)
            #pragma unroll
            for (int n = 0; n < 2; n++) a2[m][n] = (f32x4){0,0,0,0};
        for (int kt = 0; kt < 4; kt++) {
            bf16x8 x[2];
            #pragma unroll
            for (int m = 0; m < 2; m++)
                x[m] = *(const bf16x8*)&h1s[(m * 16 + c) * HS + kt * 32 + quad * 8];
            #pragma unroll
            for (int n = 0; n < 2; n++) {
                bf16x8 w = w2v[((2 * wave + n) * 4 + kt) * 64 + lane];
                #pragma unroll
                for (int m = 0; m < 2; m++)
                    a2[m][n] = __builtin_amdgcn_mfma_f32_16x16x32_bf16(w, x[m], a2[m][n], 0, 0, 0);
            }
        }
        float* os = (float*)zs;   // stride 132 floats
        #pragma unroll
        for (int n = 0; n < 2; n++) {
            int nt = 2 * wave + n;
            float4 bb = *(const float4*)&bn2[nt * 16 + quad * 4];
            #pragma unroll
            for (int m = 0; m < 2; m++) {
                f32x4 o = { a2[m][n][0] + bb.x, a2[m][n][1] + bb.y,
                            a2[m][n][2] + bb.z, a2[m][n][3] + bb.w };
                *(f32x4*)&os[(m * 16 + c) * 132 + nt * 16 + quad * 4] = o;
            }
        }
        __syncthreads();

        #pragma unroll
        for (int it = 0; it < 4; it++) {
            int idx = it * 256 + t;              // 0..1023
            int node = idx >> 5, ch = idx & 31;
            int gn = n0 + node;
            if (gn < NN_) {
                size_t gb = ((size_t)b * NN_ + gn) * F + ch * 4;
                float4 hres = *(const float4*)&h[gb];
                float4 acc = *(const float4*)&os[node * 132 + ch * 4];
                float4 o = { hres.x + acc.x, hres.y + acc.y, hres.z + acc.z, hres.w + acc.w };
                *(float4*)&out_h[gb] = o;
            }
        }
        for (int idx = t; idx < NPB2 * 12; idx += 256) {
            int node = idx / 12, j = idx % 12;
            int gn = n0 + node;
            if (gn < NN_) {
                float deg = (float)(csr_off[gn + 1] - csr_off[gn]);
                size_t ci = ((size_t)b * NN_ + gn) * 12 + j;
                out_c[ci] = coord[ci] + agg_c[ci] / fmaxf(deg, 1.0f);
            }
        }
    }
}

extern "C" void kernel_launch(void* const* d_in, const int* in_sizes, int n_in,
                              void* d_out, int out_size, void* d_ws, size_t ws_size,
                              hipStream_t stream) {
    const float* h     = (const float*)d_in[0];
    const float* coord = (const float*)d_in[1];
    const int*   ei    = (const int*)d_in[2];
    const float* ea    = (const float*)d_in[3];
    const float* We1   = (const float*)d_in[4];
    const float* be1   = (const float*)d_in[5];
    const float* We2   = (const float*)d_in[6];
    const float* be2   = (const float*)d_in[7];
    const float* Wn1   = (const float*)d_in[8];
    const float* bn1   = (const float*)d_in[9];
    const float* Wn2   = (const float*)d_in[10];
    const float* bn2   = (const float*)d_in[11];
    const float* Wc1   = (const float*)d_in[12];
    const float* bc1   = (const float*)d_in[13];
    const float* Wc2   = (const float*)d_in[14];

    float* out_h = (float*)d_out;                       // [B,N,F]
    float* out_c = out_h + (size_t)B * NN_ * F;         // [B,N,4,3]

    unsigned char* base = (unsigned char*)d_ws;
    __bf16* pw1  = (__bf16*)base;             // 36864 bf16
    __bf16* pw2  = pw1 + 36864;               // 16384
    __bf16* pwc1 = pw2 + 16384;               // 16384
    __bf16* pwc2 = pwc1 + 16384;              // 2048
    __bf16* pwn1 = pwc2 + 2048;               // 32768
    __bf16* pwn2 = pwn1 + 32768;              // 16384  -> 120832 elems = 241664 B
    unsigned char* dyn = base + 241664;

    int* csr_cnt = (int*)(dyn);               // 20000 B
    int* csr_off = (int*)(dyn + 20000);       // 20016 B
    int* csr_pos = (int*)(dyn + 40016);       // 20000 B
    int* bucket  = (int*)(dyn + 60016);       // 640000 B
    float* agg_h = (float*)(dyn + 700016);    // [B,N,HID]  5,120,000 B
    float* agg_c = agg_h + (size_t)B * NN_ * HID;            // [B,N,12] 480,000 B
    __bf16* pr   = (__bf16*)(agg_c + (size_t)B * NN_ * 12);  // 2,560,000 B
    __bf16* pc   = pr + (size_t)B * NN_ * F;                 // 2,560,000 B
    int* bar     = (int*)(dyn + 11420016);    // 12800 B tree-barrier state

    hipMemsetAsync(csr_cnt, 0, 20000, stream);
    hipMemsetAsync(bar, 0, 12800, stream);

    fused_kernel<<<GRID_BLKS, 256, 0, stream>>>(
        h, coord, ei, ea, We1, be1, We2, be2, Wn1, bn1, Wn2, bn2, Wc1, bc1, Wc2,
        pw1, pw2, pwc1, pwc2, pwn1, pwn2,
        csr_cnt, csr_off, csr_pos, bucket, agg_h, agg_c, pr, pc,
        out_h, out_c, bar);
}

// Round 5
// 263.632 us; speedup vs baseline: 5.1286x; 3.1703x over previous
//
#include <hip/hip_runtime.h>
#include <hip/hip_bf16.h>

#define B   2
#define NN_ 5000
#define NE_ 160000
#define F   128
#define HID 128
#define ED  16

typedef __bf16 bf16x8 __attribute__((ext_vector_type(8)));
typedef __bf16 bf16x4 __attribute__((ext_vector_type(4)));
typedef float  f32x4  __attribute__((ext_vector_type(4)));

#define MS  136     // edge buf row stride (17 16B-units, odd -> conflict-free b128)
#define PS  40      // xs32 row stride
#define EDG 64      // edges per chunk
#define ZS  264     // node z row stride bf16
#define HS  136     // node h1 row stride
#define NPB2 32     // nodes per block (node phase)
#define GRID_BLKS 768      // 3 blocks/CU x 256 CU, co-resident by construction
#define NTHR (GRID_BLKS*256)
#define NCHUNK 5000        // (NE_/EDG)*B
#define NGRP 24            // tree barrier: 24 groups x 32 blocks

// ================= kernel A: pack weights + zero agg | histogram | pr/pc GEMM ======
// (verbatim round-1 structure — proven correct; plain stores; the A->C dispatch
//  boundary CP writeback-invalidate provides cross-XCD visibility, as in baseline)
__global__ __launch_bounds__(512) void pack_hist_kernel(
    const float* __restrict__ We1, const float* __restrict__ We2,
    const float* __restrict__ Wc1, const float* __restrict__ Wc2,
    const float* __restrict__ Wn1, const float* __restrict__ Wn2,
    const int* __restrict__ ei,
    const float* __restrict__ h, const float* __restrict__ be1,
    __bf16* __restrict__ pw1, __bf16* __restrict__ pw2,
    __bf16* __restrict__ pwc1, __bf16* __restrict__ pwc2,
    __bf16* __restrict__ pwn1, __bf16* __restrict__ pwn2,
    float4* __restrict__ agg4, int* __restrict__ csr_cnt,
    __bf16* __restrict__ pr, __bf16* __restrict__ pc)
{
    __shared__ __align__(16) __bf16 hs[128 * MS];
    const int t = threadIdx.x;

    if (blockIdx.x < 236) {               // 236*512 = 120832 pack threads
        int idx = blockIdx.x * 512 + t;
        const float* W; __bf16* P; int KT, Nr, local;
        if (idx < 36864)       { W = We1; P = pw1;  KT = 9; Nr = 128; local = idx; }
        else if (idx < 53248)  { W = We2; P = pw2;  KT = 4; Nr = 128; local = idx - 36864; }
        else if (idx < 69632)  { W = Wc1; P = pwc1; KT = 4; Nr = 128; local = idx - 53248; }
        else if (idx < 71680)  { W = Wc2; P = pwc2; KT = 4; Nr = 4;   local = idx - 69632; }
        else if (idx < 104448) { W = Wn1; P = pwn1; KT = 8; Nr = 128; local = idx - 71680; }
        else                   { W = Wn2; P = pwn2; KT = 4; Nr = 128; local = idx - 104448; }
        int j = local & 7, lane = (local >> 3) & 63, rest = local >> 9;
        int kt = rest % KT, nt = rest / KT;
        int k = kt * 32 + (lane >> 4) * 8 + j;
        int n = nt * 16 + (lane & 15);
        float v = (n < Nr) ? W[k * Nr + n] : 0.f;
        P[local] = (__bf16)v;
        // zero agg_h+agg_c (contiguous, 350000 float4)
        float4 z4 = {0.f, 0.f, 0.f, 0.f};
        for (int i = idx; i < 350000; i += 120832) agg4[i] = z4;
        return;
    }
    if (blockIdx.x < 549) {               // 313 hist blocks
        int i = (blockIdx.x - 236) * 512 + t;
        if (i < NE_) atomicAdd(&csr_cnt[ei[i]], 1);
        return;
    }

    // ---- pr/pc GEMM: 80 blocks, reads raw We1, fuses be1 into pr ----
    const int bp = blockIdx.x - 549;      // 0..79
    const int b = bp / 40;
    const int n0 = (bp % 40) * 128;
    const int lane = t & 63, wave = t >> 6;   // wave = nt (8 feat-tiles)
    const int quad = lane >> 4, c = lane & 15;

    #pragma unroll
    for (int it = 0; it < 8; it++) {
        int idx = it * 512 + t;               // 0..4095
        int node = idx >> 5, ch = idx & 31;
        int gn = n0 + node;
        float4 v = (gn < NN_) ? *(const float4*)&h[((size_t)b * NN_ + gn) * F + ch * 4]
                              : (float4){0.f, 0.f, 0.f, 0.f};
        bf16x4 bv = {(__bf16)v.x, (__bf16)v.y, (__bf16)v.z, (__bf16)v.w};
        *(bf16x4*)&hs[node * MS + ch * 4] = bv;
    }
    __syncthreads();

    f32x4 accr[8], accc[8];
    #pragma unroll
    for (int m = 0; m < 8; m++) { accr[m] = (f32x4){0,0,0,0}; accc[m] = (f32x4){0,0,0,0}; }
    for (int kt = 0; kt < 4; kt++) {
        bf16x8 wr, wc;
        #pragma unroll
        for (int jj = 0; jj < 8; jj++) {
            int k = kt * 32 + quad * 8 + jj;
            wr[jj] = (__bf16)We1[k * HID + wave * 16 + c];           // rows 0..127
            wc[jj] = (__bf16)We1[(k + 128) * HID + wave * 16 + c];   // rows 128..255
        }
        #pragma unroll
        for (int m = 0; m < 8; m++) {
            bf16x8 x = *(const bf16x8*)&hs[(m * 16 + c) * MS + kt * 32 + quad * 8];
            accr[m] = __builtin_amdgcn_mfma_f32_16x16x32_bf16(wr, x, accr[m], 0, 0, 0);
            accc[m] = __builtin_amdgcn_mfma_f32_16x16x32_bf16(wc, x, accc[m], 0, 0, 0);
        }
    }
    float4 bb = *(const float4*)&be1[wave * 16 + quad * 4];
    #pragma unroll
    for (int m = 0; m < 8; m++) {
        int gn = n0 + m * 16 + c;
        if (gn < NN_) {
            size_t base = ((size_t)b * NN_ + gn) * F + wave * 16 + quad * 4;
            bf16x4 orr = {(__bf16)(accr[m][0] + bb.x), (__bf16)(accr[m][1] + bb.y),
                          (__bf16)(accr[m][2] + bb.z), (__bf16)(accr[m][3] + bb.w)};
            bf16x4 occ = {(__bf16)accc[m][0], (__bf16)accc[m][1], (__bf16)accc[m][2], (__bf16)accc[m][3]};
            *(bf16x4*)&pr[base] = orr;
            *(bf16x4*)&pc[base] = occ;
        }
    }
}

// ---- fence-free tree barrier: ALL RMWs RELAXED (no buffer_wbl2/buffer_inv
//      emitted). Ordering only; data visibility is via MALL atomics + first-touch
//      plain reads by design. Monotonic epoch counters, 256B-padded lines. ----
__device__ __forceinline__ void treebar(int* bar, int epoch) {
    __syncthreads();
    if (threadIdx.x == 0) {
        const int g = blockIdx.x >> 5;                     // 0..23
        int* rootcnt = bar;
        int* rootgen = bar + 64;
        int* gcnt    = bar + 128 + g * 64;
        int* ggen    = bar + 128 + NGRP * 64 + g * 64;
        int a = __hip_atomic_fetch_add(gcnt, 1, __ATOMIC_RELAXED, __HIP_MEMORY_SCOPE_AGENT);
        if (a == epoch * 32 + 31) {                        // last of group
            int r = __hip_atomic_fetch_add(rootcnt, 1, __ATOMIC_RELAXED, __HIP_MEMORY_SCOPE_AGENT);
            if (r == epoch * NGRP + (NGRP - 1)) {
                __hip_atomic_fetch_add(rootgen, 1, __ATOMIC_RELAXED, __HIP_MEMORY_SCOPE_AGENT);
            } else {
                while (__hip_atomic_fetch_add(rootgen, 0, __ATOMIC_RELAXED, __HIP_MEMORY_SCOPE_AGENT) <= epoch)
                    __builtin_amdgcn_s_sleep(8);
            }
            __hip_atomic_fetch_add(ggen, 1, __ATOMIC_RELAXED, __HIP_MEMORY_SCOPE_AGENT);
        } else {
            while (__hip_atomic_fetch_add(ggen, 0, __ATOMIC_RELAXED, __HIP_MEMORY_SCOPE_AGENT) <= epoch)
                __builtin_amdgcn_s_sleep(8);
        }
    }
    asm volatile("" ::: "memory");
    __syncthreads();
}

// ================= kernel C: scan -> scatter -> edge -> node =================
// Cross-block dataflow INSIDE this kernel goes through MALL only:
//   csr_off/csr_pos: atomicExch (scan) -> atomicAdd/plain-first-touch
//   bucket: atomicExch (scatter) -> plain first-touch reads (edge)
//   agg_h/agg_c: atomicAdd (edge) -> plain first-touch reads (node)
__global__ void __launch_bounds__(256, 3) main_kernel(
    const float* __restrict__ h, const float* __restrict__ coord,
    const int* __restrict__ ei, const float* __restrict__ ea,
    const float* __restrict__ be2, const float* __restrict__ bc1,
    const float* __restrict__ bn1, const float* __restrict__ bn2,
    const __bf16* __restrict__ pw1, const __bf16* __restrict__ pw2,
    const __bf16* __restrict__ pwc1, const __bf16* __restrict__ pwc2,
    const __bf16* __restrict__ pwn1, const __bf16* __restrict__ pwn2,
    int* __restrict__ csr_cnt, int* csr_off, int* csr_pos,
    int* bucket, float* agg_h, float* agg_c,
    const __bf16* __restrict__ pr, const __bf16* __restrict__ pc,
    float* __restrict__ out_h, float* __restrict__ out_c,
    int* bar)
{
    __shared__ __align__(16) unsigned char smem[37376];
    const int t = threadIdx.x;
    const int blk = blockIdx.x;
    const int gtid = blk * 256 + t;

    // ================= scan (blk0): csr_cnt -> csr_off/csr_pos via atomicExch =====
    if (blk == 0) {
        int* part = (int*)smem;
        int sum = 0;
        #pragma unroll
        for (int j = 0; j < 20; j++) {
            int idx = t * 20 + j;
            if (idx < NN_) sum += csr_cnt[idx];
        }
        part[t] = sum;
        __syncthreads();
        for (int off = 1; off < 256; off <<= 1) {
            int v = (t >= off) ? part[t - off] : 0;
            __syncthreads();
            part[t] += v;
            __syncthreads();
        }
        int run = part[t] - sum;
        #pragma unroll
        for (int j = 0; j < 20; j++) {
            int idx = t * 20 + j;
            if (idx < NN_) {
                atomicExch(&csr_off[idx], run);
                atomicExch(&csr_pos[idx], run);
                run += csr_cnt[idx];
            }
        }
        if (t == 0) atomicExch(&csr_off[NN_], NE_);
    }
    treebar(bar, 0);

    // ================= scatter: bucket via atomicExch =================
    if (gtid < NE_) {
        int p = atomicAdd(&csr_pos[ei[gtid]], 1);
        atomicExch(&bucket[p], gtid);
    }
    treebar(bar, 1);

    // ================= edge phase (contiguous chunk ranges, named-reg prefetch) =====
    {
        __bf16* buf1 = (__bf16*)smem;                       // 17408 B  presum -> h1 -> h2
        __bf16* buf2 = (__bf16*)(smem + 17408);             // 17408 B  xs32 -> ef
        __bf16 (*cds)[12] = (__bf16(*)[12])(smem + 34816);  // 1536 B
        int* rs    = (int*)(smem + 36352);
        int* rsN   = (int*)(smem + 36608);
        int* csN   = (int*)(smem + 36864);
        int* eidsN = (int*)(smem + 37120);                  // ends 37376

        const int lane = t & 63, wave = t >> 6;
        const int quad = lane >> 4, c = lane & 15;
        const int e4 = t >> 2, j4 = t & 3;                  // radial: 4 threads per edge
        const int eB = t >> 4, chB = t & 15;                // presum: edges eB,16+eB,32+eB,48+eB

        const bf16x8* pw1v  = (const bf16x8*)pw1;
        const bf16x8* pw2v  = (const bf16x8*)pw2;
        const bf16x8* pwc1v = (const bf16x8*)pwc1;
        const bf16x8* pwc2v = (const bf16x8*)pwc2;

        bf16x8 pcA, pcB, pcC, pcD;                          // named regs: no spill
        float crN0, crN1, crN2, ccN0, ccN1, ccN2;
        float4 eaNv;

        // contiguous chunk range per block (pr locality, serialized same-node atomics)
        const int c0 = (int)(((long long)blk * NCHUNK) / GRID_BLKS);
        const int c1 = (int)(((long long)(blk + 1) * NCHUNK) / GRID_BLKS);

        {   // cold meta for chunk c0
            const int bC = (c0 >= 2500) ? 1 : 0;
            const int p0 = (c0 - bC * 2500) * EDG;
            if (t < EDG) {
                int me = bucket[p0 + t];
                rsN[t] = ei[me]; csN[t] = ei[NE_ + me]; eidsN[t] = me;
            }
        }
        __syncthreads();
        {   // cold prefetch (pc random gather + coord + ea)
            const int bC = (c0 >= 2500) ? 1 : 0;
            const __bf16* pcb = pc + (size_t)bC * NN_ * F;
            pcA = *(const bf16x8*)(pcb + (size_t)csN[eB]      * F + chB * 8);
            pcB = *(const bf16x8*)(pcb + (size_t)csN[16 + eB] * F + chB * 8);
            pcC = *(const bf16x8*)(pcb + (size_t)csN[32 + eB] * F + chB * 8);
            pcD = *(const bf16x8*)(pcb + (size_t)csN[48 + eB] * F + chB * 8);
            const float* crp = coord + ((size_t)bC * NN_ + rsN[e4]) * 12 + j4 * 3;
            const float* ccp = coord + ((size_t)bC * NN_ + csN[e4]) * 12 + j4 * 3;
            crN0 = crp[0]; crN1 = crp[1]; crN2 = crp[2];
            ccN0 = ccp[0]; ccN1 = ccp[1]; ccN2 = ccp[2];
            eaNv = *(const float4*)(ea + (size_t)eidsN[e4] * ED + j4 * 4);
        }

        for (int cid = c0; cid < c1; cid++) {
            const int bCur = (cid >= 2500) ? 1 : 0;
            const int nid  = (cid + 1 < c1) ? (cid + 1) : cid;   // clamp
            const int bN   = (nid >= 2500) ? 1 : 0;
            const int p0n  = (nid - bN * 2500) * EDG;

            // ---- S: presum flush (pr synchronous: few distinct sorted rows, L2-hot) ----
            {
                const __bf16* prb = pr + (size_t)bCur * NN_ * F;
                bf16x8 a0 = *(const bf16x8*)(prb + (size_t)rsN[eB]      * F + chB * 8);
                bf16x8 a1 = *(const bf16x8*)(prb + (size_t)rsN[16 + eB] * F + chB * 8);
                bf16x8 a2 = *(const bf16x8*)(prb + (size_t)rsN[32 + eB] * F + chB * 8);
                bf16x8 a3 = *(const bf16x8*)(prb + (size_t)rsN[48 + eB] * F + chB * 8);
                bf16x8 o0, o1, o2, o3;
                #pragma unroll
                for (int j = 0; j < 8; j++) {
                    o0[j] = (__bf16)((float)a0[j] + (float)pcA[j]);
                    o1[j] = (__bf16)((float)a1[j] + (float)pcB[j]);
                    o2[j] = (__bf16)((float)a2[j] + (float)pcC[j]);
                    o3[j] = (__bf16)((float)a3[j] + (float)pcD[j]);
                }
                *(bf16x8*)&buf1[(eB)      * MS + chB * 8] = o0;
                *(bf16x8*)&buf1[(16 + eB) * MS + chB * 8] = o1;
                *(bf16x8*)&buf1[(32 + eB) * MS + chB * 8] = o2;
                *(bf16x8*)&buf1[(48 + eB) * MS + chB * 8] = o3;
            }
            {   // radial from prefetched coords, 4 threads/edge
                float cd0 = crN0 - ccN0, cd1 = crN1 - ccN1, cd2 = crN2 - ccN2;
                cds[e4][j4 * 3 + 0] = (__bf16)cd0;
                cds[e4][j4 * 3 + 1] = (__bf16)cd1;
                cds[e4][j4 * 3 + 2] = (__bf16)cd2;
                float px[4], ss = 0.f;
                #pragma unroll
                for (int k = 0; k < 4; k++) {
                    int sl = (lane & ~3) | k;
                    float bx = __shfl(cd0, sl, 64);
                    float by = __shfl(cd1, sl, 64);
                    float bz = __shfl(cd2, sl, 64);
                    px[k] = cd0 * bx + cd1 * by + cd2 * bz;
                    ss += px[k] * px[k];
                }
                ss += __shfl_xor(ss, 1, 64);
                ss += __shfl_xor(ss, 2, 64);
                float inv = 1.0f / fmaxf(sqrtf(ss), 1e-12f);
                bf16x4 xp = {(__bf16)(px[0] * inv), (__bf16)(px[1] * inv),
                             (__bf16)(px[2] * inv), (__bf16)(px[3] * inv)};
                *(bf16x4*)&buf2[e4 * PS + j4 * 4] = xp;
                bf16x4 bea = {(__bf16)eaNv.x, (__bf16)eaNv.y, (__bf16)eaNv.z, (__bf16)eaNv.w};
                *(bf16x4*)&buf2[e4 * PS + 16 + j4 * 4] = bea;
            }
            if (t < EDG) rs[t] = rsN[t];
            __syncthreads();

            // ---- issue next-chunk metadata (chain hides under e1) ----
            int mr = 0, mc = 0, me = 0;
            if (t < EDG) {
                me = bucket[p0n + t];
                mr = ei[me];
                mc = ei[NE_ + me];
            }

            // ===== e1: K=32 (kt=8 tile of pw1) + presum =====
            f32x4 acc1[4][2];
            #pragma unroll
            for (int m = 0; m < 4; m++)
                #pragma unroll
                for (int n = 0; n < 2; n++) acc1[m][n] = (f32x4){0,0,0,0};
            {
                bf16x8 x1[4];
                #pragma unroll
                for (int m = 0; m < 4; m++)
                    x1[m] = *(const bf16x8*)&buf2[(m * 16 + c) * PS + quad * 8];
                #pragma unroll
                for (int n = 0; n < 2; n++) {
                    bf16x8 w = pw1v[((2 * wave + n) * 9 + 8) * 64 + lane];
                    #pragma unroll
                    for (int m = 0; m < 4; m++)
                        acc1[m][n] = __builtin_amdgcn_mfma_f32_16x16x32_bf16(w, x1[m], acc1[m][n], 0, 0, 0);
                }
            }
            #pragma unroll
            for (int n = 0; n < 2; n++) {
                int nt = 2 * wave + n;
                #pragma unroll
                for (int m = 0; m < 4; m++) {
                    int row = m * 16 + c;
                    bf16x4 pp = *(const bf16x4*)&buf1[row * MS + nt * 16 + quad * 4];
                    bf16x4 o = { (__bf16)fmaxf(acc1[m][n][0] + (float)pp[0], 0.f),
                                 (__bf16)fmaxf(acc1[m][n][1] + (float)pp[1], 0.f),
                                 (__bf16)fmaxf(acc1[m][n][2] + (float)pp[2], 0.f),
                                 (__bf16)fmaxf(acc1[m][n][3] + (float)pp[3], 0.f) };
                    *(bf16x4*)&buf1[row * MS + nt * 16 + quad * 4] = o;
                }
            }
            if (t < EDG) { rsN[t] = mr; csN[t] = mc; eidsN[t] = me; }
            __syncthreads();

            // ---- issue next-chunk prefetch (hides under e2/c1/c2/seg-reduce) ----
            {
                const __bf16* pcb = pc + (size_t)bN * NN_ * F;
                pcA = *(const bf16x8*)(pcb + (size_t)csN[eB]      * F + chB * 8);
                pcB = *(const bf16x8*)(pcb + (size_t)csN[16 + eB] * F + chB * 8);
                pcC = *(const bf16x8*)(pcb + (size_t)csN[32 + eB] * F + chB * 8);
                pcD = *(const bf16x8*)(pcb + (size_t)csN[48 + eB] * F + chB * 8);
                const float* crp = coord + ((size_t)bN * NN_ + rsN[e4]) * 12 + j4 * 3;
                const float* ccp = coord + ((size_t)bN * NN_ + csN[e4]) * 12 + j4 * 3;
                crN0 = crp[0]; crN1 = crp[1]; crN2 = crp[2];
                ccN0 = ccp[0]; ccN1 = ccp[1]; ccN2 = ccp[2];
                eaNv = *(const float4*)(ea + (size_t)eidsN[e4] * ED + j4 * 4);
            }

            // ===== e2: h1 @ We2 -> ef (buf2, stride MS) =====
            f32x4 acc2[4][2];
            #pragma unroll
            for (int m = 0; m < 4; m++)
                #pragma unroll
                for (int n = 0; n < 2; n++) acc2[m][n] = (f32x4){0,0,0,0};
            for (int kt = 0; kt < 4; kt++) {
                bf16x8 x[4];
                #pragma unroll
                for (int m = 0; m < 4; m++)
                    x[m] = *(const bf16x8*)&buf1[(m * 16 + c) * MS + kt * 32 + quad * 8];
                #pragma unroll
                for (int n = 0; n < 2; n++) {
                    bf16x8 w = pw2v[((2 * wave + n) * 4 + kt) * 64 + lane];
                    #pragma unroll
                    for (int m = 0; m < 4; m++)
                        acc2[m][n] = __builtin_amdgcn_mfma_f32_16x16x32_bf16(w, x[m], acc2[m][n], 0, 0, 0);
                }
            }
            #pragma unroll
            for (int n = 0; n < 2; n++) {
                int nt = 2 * wave + n;
                float4 bb = *(const float4*)&be2[nt * 16 + quad * 4];
                #pragma unroll
                for (int m = 0; m < 4; m++) {
                    int row = m * 16 + c;
                    bf16x4 o = { (__bf16)fmaxf(acc2[m][n][0] + bb.x, 0.f),
                                 (__bf16)fmaxf(acc2[m][n][1] + bb.y, 0.f),
                                 (__bf16)fmaxf(acc2[m][n][2] + bb.z, 0.f),
                                 (__bf16)fmaxf(acc2[m][n][3] + bb.w, 0.f) };
                    *(bf16x4*)&buf2[row * MS + nt * 16 + quad * 4] = o;
                }
            }
            __syncthreads();   // buf2 (ef) stable from here on

            // ===== c1: ef @ Wc1 -> buf1 =====
            f32x4 acc3[4][2];
            #pragma unroll
            for (int m = 0; m < 4; m++)
                #pragma unroll
                for (int n = 0; n < 2; n++) acc3[m][n] = (f32x4){0,0,0,0};
            for (int kt = 0; kt < 4; kt++) {
                bf16x8 x[4];
                #pragma unroll
                for (int m = 0; m < 4; m++)
                    x[m] = *(const bf16x8*)&buf2[(m * 16 + c) * MS + kt * 32 + quad * 8];
                #pragma unroll
                for (int n = 0; n < 2; n++) {
                    bf16x8 w = pwc1v[((2 * wave + n) * 4 + kt) * 64 + lane];
                    #pragma unroll
                    for (int m = 0; m < 4; m++)
                        acc3[m][n] = __builtin_amdgcn_mfma_f32_16x16x32_bf16(w, x[m], acc3[m][n], 0, 0, 0);
                }
            }
            #pragma unroll
            for (int n = 0; n < 2; n++) {
                int nt = 2 * wave + n;
                float4 bb = *(const float4*)&bc1[nt * 16 + quad * 4];
                #pragma unroll
                for (int m = 0; m < 4; m++) {
                    int row = m * 16 + c;
                    bf16x4 o = { (__bf16)fmaxf(acc3[m][n][0] + bb.x, 0.f),
                                 (__bf16)fmaxf(acc3[m][n][1] + bb.y, 0.f),
                                 (__bf16)fmaxf(acc3[m][n][2] + bb.z, 0.f),
                                 (__bf16)fmaxf(acc3[m][n][3] + bb.w, 0.f) };
                    *(bf16x4*)&buf1[row * MS + nt * 16 + quad * 4] = o;
                }
            }
            __syncthreads();

            // ===== c2: wave owns m-tile = wave =====
            f32x4 accw = (f32x4){0,0,0,0};
            for (int kt = 0; kt < 4; kt++) {
                bf16x8 x = *(const bf16x8*)&buf1[(wave * 16 + c) * MS + kt * 32 + quad * 8];
                accw = __builtin_amdgcn_mfma_f32_16x16x32_bf16(pwc2v[kt * 64 + lane], x, accw, 0, 0, 0);
            }
            if (quad == 0) {
                int e = wave * 16 + c;
                #pragma unroll
                for (int j = 0; j < 12; j++)
                    cds[e][j] = (__bf16)((float)cds[e][j] * accw[j / 3]);
            }

            // ===== agg_h seg-reduce (reads only buf2; overlaps other waves' c2) =====
            {
                float* aggh_b = agg_h + (size_t)bCur * NN_ * HID;
                const int col = t & 127, seg = t >> 7;
                float run = 0.f;
                int cur = rs[seg * 32];
                for (int e = seg * 32; e < seg * 32 + 32; e++) {
                    int r = rs[e];
                    float v = (float)buf2[e * MS + col];
                    if (r != cur) {
                        atomicAdd(&aggh_b[(size_t)cur * HID + col], run);
                        run = 0.f; cur = r;
                    }
                    run += v;
                }
                atomicAdd(&aggh_b[(size_t)cur * HID + col], run);
            }
            __syncthreads();   // cds updates visible

            if (t < 24) {
                float* aggc_b = agg_c + (size_t)bCur * NN_ * 12;
                const int j = t % 12, q = t / 12;
                float run = 0.f;
                int cur = rs[q * 32];
                for (int e = q * 32; e < q * 32 + 32; e++) {
                    int r = rs[e];
                    float v = (float)cds[e][j];
                    if (r != cur) {
                        atomicAdd(&aggc_b[(size_t)cur * 12 + j], run);
                        run = 0.f; cur = r;
                    }
                    run += v;
                }
                atomicAdd(&aggc_b[(size_t)cur * 12 + j], run);
            }
            __syncthreads();   // protect LDS before next chunk's S-write
        }
    }
    treebar(bar, 2);

    // ================= node phase =================
    if (blk < 314) {
        __bf16* zs  = (__bf16*)smem;                 // 16896 B, reused as os (fp32, stride 132)
        __bf16* h1s = (__bf16*)(smem + 16896);       // 8704 B
        const int b  = blk / 157;
        const int n0 = (blk % 157) * NPB2;
        const int lane = t & 63, wave = t >> 6;
        const int quad = lane >> 4, c = lane & 15;

        #pragma unroll
        for (int it = 0; it < 8; it++) {
            int idx = it * 256 + t;              // 0..2047
            int node = idx >> 6, ch = idx & 63;  // ch 0..31 = h, 32..63 = agg_h
            int gn = n0 + node;
            float4 v = (float4){0.f, 0.f, 0.f, 0.f};
            if (gn < NN_) {
                const float* src = (ch < 32) ? &h[((size_t)b * NN_ + gn) * F + ch * 4]
                                             : &agg_h[((size_t)b * NN_ + gn) * HID + (ch - 32) * 4];
                v = *(const float4*)src;
            }
            bf16x4 bv = {(__bf16)v.x, (__bf16)v.y, (__bf16)v.z, (__bf16)v.w};
            *(bf16x4*)&zs[node * ZS + ch * 4] = bv;
        }
        __syncthreads();

        const bf16x8* w1v = (const bf16x8*)pwn1;
        const bf16x8* w2v = (const bf16x8*)pwn2;
        f32x4 a1[2][2];
        #pragma unroll
        for (int m = 0; m < 2; m++)
            #pragma unroll
            for (int n = 0; n < 2; n++) a1[m][n] = (f32x4){0,0,0,0};
        for (int kt = 0; kt < 8; kt++) {
            bf16x8 x[2];
            #pragma unroll
            for (int m = 0; m < 2; m++)
                x[m] = *(const bf16x8*)&zs[(m * 16 + c) * ZS + kt * 32 + quad * 8];
            #pragma unroll
            for (int n = 0; n < 2; n++) {
                bf16x8 w = w1v[((2 * wave + n) * 8 + kt) * 64 + lane];
                #pragma unroll
                for (int m = 0; m < 2; m++)
                    a1[m][n] = __builtin_amdgcn_mfma_f32_16x16x32_bf16(w, x[m], a1[m][n], 0, 0, 0);
            }
        }
        __syncthreads();
        #pragma unroll
        for (int n = 0; n < 2; n++) {
            int nt = 2 * wave + n;
            float4 bb = *(const float4*)&bn1[nt * 16 + quad * 4];
            #pragma unroll
            for (int m = 0; m < 2; m++) {
                bf16x4 o = { (__bf16)fmaxf(a1[m][n][0] + bb.x, 0.f),
                             (__bf16)fmaxf(a1[m][n][1] + bb.y, 0.f),
                             (__bf16)fmaxf(a1[m][n][2] + bb.z, 0.f),
                             (__bf16)fmaxf(a1[m][n][3] + bb.w, 0.f) };
                *(bf16x4*)&h1s[(m * 16 + c) * HS + nt * 16 + quad * 4] = o;
            }
        }
        __syncthreads();

        f32x4 a2[2][2];
        #pragma unroll
        for (int m = 0; m < 2; m++)
            #pragma unroll
            for (int n = 0; n < 2; n++) a2[m][n] = (f32x4){0,0,0,0};
        for (int kt = 0; kt < 4; kt++) {
            bf16x8 x[2];
            #pragma unroll
            for (int m = 0; m < 2; m++)
                x[m] = *(const bf16x8*)&h1s[(m * 16 + c) * HS + kt * 32 + quad * 8];
            #pragma unroll
            for (int n = 0; n < 2; n++) {
                bf16x8 w = w2v[((2 * wave + n) * 4 + kt) * 64 + lane];
                #pragma unroll
                for (int m = 0; m < 2; m++)
                    a2[m][n] = __builtin_amdgcn_mfma_f32_16x16x32_bf16(w, x[m], a2[m][n], 0, 0, 0);
            }
        }
        float* os = (float*)zs;   // stride 132 floats
        #pragma unroll
        for (int n = 0; n < 2; n++) {
            int nt = 2 * wave + n;
            float4 bb = *(const float4*)&bn2[nt * 16 + quad * 4];
            #pragma unroll
            for (int m = 0; m < 2; m++) {
                f32x4 o = { a2[m][n][0] + bb.x, a2[m][n][1] + bb.y,
                            a2[m][n][2] + bb.z, a2[m][n][3] + bb.w };
                *(f32x4*)&os[(m * 16 + c) * 132 + nt * 16 + quad * 4] = o;
            }
        }
        __syncthreads();

        #pragma unroll
        for (int it = 0; it < 4; it++) {
            int idx = it * 256 + t;              // 0..1023
            int node = idx >> 5, ch = idx & 31;
            int gn = n0 + node;
            if (gn < NN_) {
                size_t gb = ((size_t)b * NN_ + gn) * F + ch * 4;
                float4 hres = *(const float4*)&h[gb];
                float4 acc = *(const float4*)&os[node * 132 + ch * 4];
                float4 o = { hres.x + acc.x, hres.y + acc.y, hres.z + acc.z, hres.w + acc.w };
                *(float4*)&out_h[gb] = o;
            }
        }
        for (int idx = t; idx < NPB2 * 12; idx += 256) {
            int node = idx / 12, j = idx % 12;
            int gn = n0 + node;
            if (gn < NN_) {
                float deg = (float)(csr_off[gn + 1] - csr_off[gn]);
                size_t ci = ((size_t)b * NN_ + gn) * 12 + j;
                out_c[ci] = coord[ci] + agg_c[ci] / fmaxf(deg, 1.0f);
            }
        }
    }
}

extern "C" void kernel_launch(void* const* d_in, const int* in_sizes, int n_in,
                              void* d_out, int out_size, void* d_ws, size_t ws_size,
                              hipStream_t stream) {
    const float* h     = (const float*)d_in[0];
    const float* coord = (const float*)d_in[1];
    const int*   ei    = (const int*)d_in[2];
    const float* ea    = (const float*)d_in[3];
    const float* We1   = (const float*)d_in[4];
    const float* be1   = (const float*)d_in[5];
    const float* We2   = (const float*)d_in[6];
    const float* be2   = (const float*)d_in[7];
    const float* Wn1   = (const float*)d_in[8];
    const float* bn1   = (const float*)d_in[9];
    const float* Wn2   = (const float*)d_in[10];
    const float* bn2   = (const float*)d_in[11];
    const float* Wc1   = (const float*)d_in[12];
    const float* bc1   = (const float*)d_in[13];
    const float* Wc2   = (const float*)d_in[14];

    float* out_h = (float*)d_out;                       // [B,N,F]
    float* out_c = out_h + (size_t)B * NN_ * F;         // [B,N,4,3]

    unsigned char* base = (unsigned char*)d_ws;
    __bf16* pw1  = (__bf16*)base;             // 36864 bf16
    __bf16* pw2  = pw1 + 36864;               // 16384
    __bf16* pwc1 = pw2 + 16384;               // 16384
    __bf16* pwc2 = pwc1 + 16384;              // 2048
    __bf16* pwn1 = pwc2 + 2048;               // 32768
    __bf16* pwn2 = pwn1 + 32768;              // 16384  -> 120832 elems = 241664 B
    unsigned char* dyn = base + 241664;

    int* bar     = (int*)(dyn);               // 12800 B tree-barrier state
    int* csr_cnt = (int*)(dyn + 12800);       // 20000 B
    int* csr_off = (int*)(dyn + 32800);       // 20016 B
    int* csr_pos = (int*)(dyn + 52816);       // 20000 B
    int* bucket  = (int*)(dyn + 72816);       // 640000 B
    float* agg_h = (float*)(dyn + 712816);    // [B,N,HID]  5,120,000 B (16-aligned)
    float* agg_c = agg_h + (size_t)B * NN_ * HID;            // [B,N,12] 480,000 B
    __bf16* pr   = (__bf16*)(agg_c + (size_t)B * NN_ * 12);  // 2,560,000 B
    __bf16* pc   = pr + (size_t)B * NN_ * F;                 // 2,560,000 B

    hipMemsetAsync(dyn, 0, 32800, stream);    // bar + csr_cnt in one blit

    pack_hist_kernel<<<629, 512, 0, stream>>>(We1, We2, Wc1, Wc2, Wn1, Wn2, ei, h, be1,
                                              pw1, pw2, pwc1, pwc2, pwn1, pwn2,
                                              (float4*)agg_h, csr_cnt, pr, pc);

    main_kernel<<<GRID_BLKS, 256, 0, stream>>>(
        h, coord, ei, ea, be2, bc1, bn1, bn2,
        pw1, pw2, pwc1, pwc2, pwn1, pwn2,
        csr_cnt, csr_off, csr_pos, bucket, agg_h, agg_c, pr, pc,
        out_h, out_c, bar);
}

// Round 6
// 197.784 us; speedup vs baseline: 6.8360x; 1.3329x over previous
//
#include <hip/hip_runtime.h>
#include <hip/hip_bf16.h>

#define B   2
#define NN_ 5000
#define NE_ 160000
#define F   128
#define HID 128
#define ED  16

typedef __bf16 bf16x8 __attribute__((ext_vector_type(8)));
typedef __bf16 bf16x4 __attribute__((ext_vector_type(4)));
typedef float  f32x4  __attribute__((ext_vector_type(4)));

#define MS  136   // edge buf row stride (17 16B-units, odd -> conflict-free b128)
#define PS  40    // xs32 row stride
#define EDG 64    // edges per block
#define ZS  264   // node z row stride bf16
#define HS  136   // node h1 row stride
#define NPB2 32   // nodes per block (node kernel)

// ================= kernel A: pack weights + zero agg | histogram | pr/pc GEMM ======
// (verbatim round-5 kernel A — harness-verified)
__global__ __launch_bounds__(512) void pack_hist_kernel(
    const float* __restrict__ We1, const float* __restrict__ We2,
    const float* __restrict__ Wc1, const float* __restrict__ Wc2,
    const float* __restrict__ Wn1, const float* __restrict__ Wn2,
    const int* __restrict__ ei,
    const float* __restrict__ h, const float* __restrict__ be1,
    __bf16* __restrict__ pw1, __bf16* __restrict__ pw2,
    __bf16* __restrict__ pwc1, __bf16* __restrict__ pwc2,
    __bf16* __restrict__ pwn1, __bf16* __restrict__ pwn2,
    float4* __restrict__ agg4, int* __restrict__ csr_cnt,
    __bf16* __restrict__ pr, __bf16* __restrict__ pc)
{
    __shared__ __align__(16) __bf16 hs[128 * MS];
    const int t = threadIdx.x;

    if (blockIdx.x < 236) {               // 236*512 = 120832 pack threads
        int idx = blockIdx.x * 512 + t;
        const float* W; __bf16* P; int KT, Nr, local;
        if (idx < 36864)       { W = We1; P = pw1;  KT = 9; Nr = 128; local = idx; }
        else if (idx < 53248)  { W = We2; P = pw2;  KT = 4; Nr = 128; local = idx - 36864; }
        else if (idx < 69632)  { W = Wc1; P = pwc1; KT = 4; Nr = 128; local = idx - 53248; }
        else if (idx < 71680)  { W = Wc2; P = pwc2; KT = 4; Nr = 4;   local = idx - 69632; }
        else if (idx < 104448) { W = Wn1; P = pwn1; KT = 8; Nr = 128; local = idx - 71680; }
        else                   { W = Wn2; P = pwn2; KT = 4; Nr = 128; local = idx - 104448; }
        int j = local & 7, lane = (local >> 3) & 63, rest = local >> 9;
        int kt = rest % KT, nt = rest / KT;
        int k = kt * 32 + (lane >> 4) * 8 + j;
        int n = nt * 16 + (lane & 15);
        float v = (n < Nr) ? W[k * Nr + n] : 0.f;
        P[local] = (__bf16)v;
        // zero agg_h+agg_c (contiguous, 350000 float4)
        float4 z4 = {0.f, 0.f, 0.f, 0.f};
        for (int i = idx; i < 350000; i += 120832) agg4[i] = z4;
        return;
    }
    if (blockIdx.x < 549) {               // 313 hist blocks
        int i = (blockIdx.x - 236) * 512 + t;
        if (i < NE_) atomicAdd(&csr_cnt[ei[i]], 1);
        return;
    }

    // ---- pr/pc GEMM: 80 blocks, reads raw We1, fuses be1 into pr ----
    const int bp = blockIdx.x - 549;      // 0..79
    const int b = bp / 40;
    const int n0 = (bp % 40) * 128;
    const int lane = t & 63, wave = t >> 6;   // wave = nt (8 feat-tiles)
    const int quad = lane >> 4, c = lane & 15;

    #pragma unroll
    for (int it = 0; it < 8; it++) {
        int idx = it * 512 + t;               // 0..4095
        int node = idx >> 5, ch = idx & 31;
        int gn = n0 + node;
        float4 v = (gn < NN_) ? *(const float4*)&h[((size_t)b * NN_ + gn) * F + ch * 4]
                              : (float4){0.f, 0.f, 0.f, 0.f};
        bf16x4 bv = {(__bf16)v.x, (__bf16)v.y, (__bf16)v.z, (__bf16)v.w};
        *(bf16x4*)&hs[node * MS + ch * 4] = bv;
    }
    __syncthreads();

    f32x4 accr[8], accc[8];
    #pragma unroll
    for (int m = 0; m < 8; m++) { accr[m] = (f32x4){0,0,0,0}; accc[m] = (f32x4){0,0,0,0}; }
    for (int kt = 0; kt < 4; kt++) {
        bf16x8 wr, wc;
        #pragma unroll
        for (int jj = 0; jj < 8; jj++) {
            int k = kt * 32 + quad * 8 + jj;
            wr[jj] = (__bf16)We1[k * HID + wave * 16 + c];           // rows 0..127
            wc[jj] = (__bf16)We1[(k + 128) * HID + wave * 16 + c];   // rows 128..255
        }
        #pragma unroll
        for (int m = 0; m < 8; m++) {
            bf16x8 x = *(const bf16x8*)&hs[(m * 16 + c) * MS + kt * 32 + quad * 8];
            accr[m] = __builtin_amdgcn_mfma_f32_16x16x32_bf16(wr, x, accr[m], 0, 0, 0);
            accc[m] = __builtin_amdgcn_mfma_f32_16x16x32_bf16(wc, x, accc[m], 0, 0, 0);
        }
    }
    float4 bb = *(const float4*)&be1[wave * 16 + quad * 4];
    #pragma unroll
    for (int m = 0; m < 8; m++) {
        int gn = n0 + m * 16 + c;
        if (gn < NN_) {
            size_t base = ((size_t)b * NN_ + gn) * F + wave * 16 + quad * 4;
            bf16x4 orr = {(__bf16)(accr[m][0] + bb.x), (__bf16)(accr[m][1] + bb.y),
                          (__bf16)(accr[m][2] + bb.z), (__bf16)(accr[m][3] + bb.w)};
            bf16x4 occ = {(__bf16)accc[m][0], (__bf16)accc[m][1], (__bf16)accc[m][2], (__bf16)accc[m][3]};
            *(bf16x4*)&pr[base] = orr;
            *(bf16x4*)&pc[base] = occ;
        }
    }
}

__global__ __launch_bounds__(512) void scan_kernel(const int* __restrict__ csr_cnt,
                                                   int* __restrict__ csr_off, int* __restrict__ csr_pos)
{
    __shared__ int part[512];
    const int t = threadIdx.x;
    int sum = 0;
    #pragma unroll
    for (int j = 0; j < 10; j++) {
        int idx = t * 10 + j;
        if (idx < NN_) sum += csr_cnt[idx];
    }
    part[t] = sum;
    __syncthreads();
    for (int off = 1; off < 512; off <<= 1) {
        int v = (t >= off) ? part[t - off] : 0;
        __syncthreads();
        part[t] += v;
        __syncthreads();
    }
    int run = part[t] - sum;
    #pragma unroll
    for (int j = 0; j < 10; j++) {
        int idx = t * 10 + j;
        if (idx < NN_) { csr_off[idx] = run; csr_pos[idx] = run; run += csr_cnt[idx]; }
    }
    if (t == 0) csr_off[NN_] = NE_;
}

__global__ __launch_bounds__(512) void scatter_kernel(const int* __restrict__ ei,
                                                      int* __restrict__ csr_pos,
                                                      int* __restrict__ bucket)
{
    int i = blockIdx.x * 512 + threadIdx.x;
    if (i < NE_) {
        int p = atomicAdd(&csr_pos[ei[i]], 1);
        bucket[p] = i;
    }
}

// ------- edge kernel: 512 threads / 8 waves, 1 nt-tile per wave -------
// Same work as the 4-wave baseline but 2x the resident waves per block:
// halves per-wave acc pressure (VGPR ~60) and lifts occupancy 34% -> ~75%.
__global__ __launch_bounds__(512, 6) void edge_kernel(
    const __bf16* __restrict__ pr, const __bf16* __restrict__ pc,
    const float* __restrict__ coord,
    const int* __restrict__ ei, const float* __restrict__ ea,
    const int* __restrict__ bucket,
    const float* __restrict__ be2, const float* __restrict__ bc1,
    const __bf16* __restrict__ pw1, const __bf16* __restrict__ pw2,
    const __bf16* __restrict__ pwc1, const __bf16* __restrict__ pwc2,
    float* __restrict__ agg_h, float* __restrict__ agg_c)
{
    __shared__ __align__(16) __bf16 buf1[EDG * MS];  // presum -> h1 -> h2
    __shared__ __align__(16) __bf16 buf2[EDG * MS];  // xs32 (stride PS) -> ef
    __shared__ __bf16 cds[EDG][12];
    __shared__ int rs[EDG], cs[EDG], eids[EDG];

    const int t = threadIdx.x;            // 0..511
    const int b = blockIdx.y;
    const int p0 = blockIdx.x * EDG;
    const int lane = t & 63, wave = t >> 6;   // wave 0..7 = nt
    const int quad = lane >> 4, c = lane & 15;

    if (t < EDG) {
        int me = bucket[p0 + t];
        eids[t] = me;
        rs[t] = ei[me]; cs[t] = ei[NE_ + me];
    }
    __syncthreads();

    // ---- stage presum = pr[row] + pc[col] into buf1 (coalesced, 2 iters) ----
    const __bf16* prb = pr + (size_t)b * NN_ * F;
    const __bf16* pcb = pc + (size_t)b * NN_ * F;
    #pragma unroll
    for (int it = 0; it < 2; it++) {
        int idx = it * 512 + t;           // 0..1023: 64 edges x 16 chunks of 8
        int e = idx >> 4, ch = idx & 15;
        bf16x8 a = *(const bf16x8*)(prb + (size_t)rs[e] * F + ch * 8);
        bf16x8 v = *(const bf16x8*)(pcb + (size_t)cs[e] * F + ch * 8);
        bf16x8 o;
        #pragma unroll
        for (int j = 0; j < 8; j++) o[j] = (__bf16)((float)a[j] + (float)v[j]);
        *(bf16x8*)&buf1[e * MS + ch * 8] = o;
    }
    // ---- radial + ea: 4 threads/edge (threads 0..255), wave-parallel shuffle ----
    if (t < 256) {
        const int e4 = t >> 2, j4 = t & 3;
        const float* crp = coord + ((size_t)b * NN_ + rs[e4]) * 12 + j4 * 3;
        const float* ccp = coord + ((size_t)b * NN_ + cs[e4]) * 12 + j4 * 3;
        float cd0 = crp[0] - ccp[0], cd1 = crp[1] - ccp[1], cd2 = crp[2] - ccp[2];
        cds[e4][j4 * 3 + 0] = (__bf16)cd0;
        cds[e4][j4 * 3 + 1] = (__bf16)cd1;
        cds[e4][j4 * 3 + 2] = (__bf16)cd2;
        float px[4], ss = 0.f;
        #pragma unroll
        for (int k = 0; k < 4; k++) {
            int sl = (lane & ~3) | k;
            float bx = __shfl(cd0, sl, 64);
            float by = __shfl(cd1, sl, 64);
            float bz = __shfl(cd2, sl, 64);
            px[k] = cd0 * bx + cd1 * by + cd2 * bz;
            ss += px[k] * px[k];
        }
        ss += __shfl_xor(ss, 1, 64);
        ss += __shfl_xor(ss, 2, 64);
        float inv = 1.0f / fmaxf(sqrtf(ss), 1e-12f);
        bf16x4 xp = {(__bf16)(px[0] * inv), (__bf16)(px[1] * inv),
                     (__bf16)(px[2] * inv), (__bf16)(px[3] * inv)};
        *(bf16x4*)&buf2[e4 * PS + j4 * 4] = xp;
        float4 v = *(const float4*)(ea + (size_t)eids[e4] * ED + j4 * 4);
        bf16x4 bea = {(__bf16)v.x, (__bf16)v.y, (__bf16)v.z, (__bf16)v.w};
        *(bf16x4*)&buf2[e4 * PS + 16 + j4 * 4] = bea;
    }
    __syncthreads();

    const bf16x8* pw1v  = (const bf16x8*)pw1;
    const bf16x8* pw2v  = (const bf16x8*)pw2;
    const bf16x8* pwc1v = (const bf16x8*)pwc1;
    const bf16x8* pwc2v = (const bf16x8*)pwc2;

    // ===== e1: K=32 (kt=8 tile of pw1) + presum; wave owns nt = wave =====
    f32x4 acc1[4];
    #pragma unroll
    for (int m = 0; m < 4; m++) acc1[m] = (f32x4){0,0,0,0};
    {
        bf16x8 w = pw1v[(wave * 9 + 8) * 64 + lane];
        #pragma unroll
        for (int m = 0; m < 4; m++) {
            bf16x8 x1 = *(const bf16x8*)&buf2[(m * 16 + c) * PS + quad * 8];
            acc1[m] = __builtin_amdgcn_mfma_f32_16x16x32_bf16(w, x1, acc1[m], 0, 0, 0);
        }
    }
    #pragma unroll
    for (int m = 0; m < 4; m++) {
        int row = m * 16 + c;
        bf16x4 pp = *(const bf16x4*)&buf1[row * MS + wave * 16 + quad * 4];
        bf16x4 o = { (__bf16)fmaxf(acc1[m][0] + (float)pp[0], 0.f),
                     (__bf16)fmaxf(acc1[m][1] + (float)pp[1], 0.f),
                     (__bf16)fmaxf(acc1[m][2] + (float)pp[2], 0.f),
                     (__bf16)fmaxf(acc1[m][3] + (float)pp[3], 0.f) };
        *(bf16x4*)&buf1[row * MS + wave * 16 + quad * 4] = o;
    }
    __syncthreads();

    // ===== e2: h1 @ We2 -> ef (buf2, stride MS) =====
    f32x4 acc2[4];
    #pragma unroll
    for (int m = 0; m < 4; m++) acc2[m] = (f32x4){0,0,0,0};
    for (int kt = 0; kt < 4; kt++) {
        bf16x8 w = pw2v[(wave * 4 + kt) * 64 + lane];
        #pragma unroll
        for (int m = 0; m < 4; m++) {
            bf16x8 x = *(const bf16x8*)&buf1[(m * 16 + c) * MS + kt * 32 + quad * 8];
            acc2[m] = __builtin_amdgcn_mfma_f32_16x16x32_bf16(w, x, acc2[m], 0, 0, 0);
        }
    }
    {
        float4 bb = *(const float4*)&be2[wave * 16 + quad * 4];
        #pragma unroll
        for (int m = 0; m < 4; m++) {
            int row = m * 16 + c;
            bf16x4 o = { (__bf16)fmaxf(acc2[m][0] + bb.x, 0.f),
                         (__bf16)fmaxf(acc2[m][1] + bb.y, 0.f),
                         (__bf16)fmaxf(acc2[m][2] + bb.z, 0.f),
                         (__bf16)fmaxf(acc2[m][3] + bb.w, 0.f) };
            *(bf16x4*)&buf2[row * MS + wave * 16 + quad * 4] = o;
        }
    }
    __syncthreads();   // buf2 (ef) stable from here on

    // ===== c1: ef @ Wc1 -> buf1 =====
    f32x4 acc3[4];
    #pragma unroll
    for (int m = 0; m < 4; m++) acc3[m] = (f32x4){0,0,0,0};
    for (int kt = 0; kt < 4; kt++) {
        bf16x8 w = pwc1v[(wave * 4 + kt) * 64 + lane];
        #pragma unroll
        for (int m = 0; m < 4; m++) {
            bf16x8 x = *(const bf16x8*)&buf2[(m * 16 + c) * MS + kt * 32 + quad * 8];
            acc3[m] = __builtin_amdgcn_mfma_f32_16x16x32_bf16(w, x, acc3[m], 0, 0, 0);
        }
    }
    {
        float4 bb = *(const float4*)&bc1[wave * 16 + quad * 4];
        #pragma unroll
        for (int m = 0; m < 4; m++) {
            int row = m * 16 + c;
            bf16x4 o = { (__bf16)fmaxf(acc3[m][0] + bb.x, 0.f),
                         (__bf16)fmaxf(acc3[m][1] + bb.y, 0.f),
                         (__bf16)fmaxf(acc3[m][2] + bb.z, 0.f),
                         (__bf16)fmaxf(acc3[m][3] + bb.w, 0.f) };
            *(bf16x4*)&buf1[row * MS + wave * 16 + quad * 4] = o;
        }
    }
    __syncthreads();

    // ===== c2: waves 0..3 each own m-tile = wave =====
    if (wave < 4) {
        f32x4 accw = (f32x4){0,0,0,0};
        for (int kt = 0; kt < 4; kt++) {
            bf16x8 x = *(const bf16x8*)&buf1[(wave * 16 + c) * MS + kt * 32 + quad * 8];
            accw = __builtin_amdgcn_mfma_f32_16x16x32_bf16(pwc2v[kt * 64 + lane], x, accw, 0, 0, 0);
        }
        if (quad == 0) {
            int e = wave * 16 + c;
            #pragma unroll
            for (int j = 0; j < 12; j++)
                cds[e][j] = (__bf16)((float)cds[e][j] * accw[j / 3]);
        }
    }

    // ===== agg_h seg-reduce (reads only buf2 — runs while waves 0..3 finish c2) =====
    {
        float* aggh_b = agg_h + (size_t)b * NN_ * HID;
        const int col = t & 127, seg = t >> 7;    // 4 segs x 16 edges
        float run = 0.f;
        int cur = rs[seg * 16];
        for (int e = seg * 16; e < seg * 16 + 16; e++) {
            int r = rs[e];
            float v = (float)buf2[e * MS + col];
            if (r != cur) {
                atomicAdd(&aggh_b[(size_t)cur * HID + col], run);
                run = 0.f; cur = r;
            }
            run += v;
        }
        atomicAdd(&aggh_b[(size_t)cur * HID + col], run);
    }
    __syncthreads();   // cds updates visible

    if (t < 24) {
        float* aggc_b = agg_c + (size_t)b * NN_ * 12;
        const int j = t % 12, q = t / 12;         // 2 segs x 32 edges
        float run = 0.f;
        int cur = rs[q * 32];
        for (int e = q * 32; e < q * 32 + 32; e++) {
            int r = rs[e];
            float v = (float)cds[e][j];
            if (r != cur) {
                atomicAdd(&aggc_b[(size_t)cur * 12 + j], run);
                run = 0.f; cur = r;
            }
            run += v;
        }
        atomicAdd(&aggc_b[(size_t)cur * 12 + j], run);
    }
}

// ------- node kernel: MFMA bf16 MLP + residual + fused coord update (verified) ------
__global__ __launch_bounds__(256) void node_kernel(
    const float* __restrict__ h, const float* __restrict__ agg_h,
    const float* __restrict__ agg_c, const float* __restrict__ coord,
    const int* __restrict__ csr_off,
    const __bf16* __restrict__ pwn1, const float* __restrict__ bn1,
    const __bf16* __restrict__ pwn2, const float* __restrict__ bn2,
    float* __restrict__ out_h, float* __restrict__ out_c)
{
    __shared__ __align__(16) __bf16 zs[NPB2 * ZS];   // reused as os (fp32, stride 132)
    __shared__ __align__(16) __bf16 h1s[NPB2 * HS];
    const int t = threadIdx.x;
    const int b = blockIdx.y;
    const int n0 = blockIdx.x * NPB2;
    const int lane = t & 63, wave = t >> 6;
    const int quad = lane >> 4, c = lane & 15;

    #pragma unroll
    for (int it = 0; it < 8; it++) {
        int idx = it * 256 + t;              // 0..2047
        int node = idx >> 6, ch = idx & 63;  // ch 0..31 = h, 32..63 = agg_h
        int gn = n0 + node;
        float4 v = (float4){0.f, 0.f, 0.f, 0.f};
        if (gn < NN_) {
            const float* src = (ch < 32) ? &h[((size_t)b * NN_ + gn) * F + ch * 4]
                                         : &agg_h[((size_t)b * NN_ + gn) * HID + (ch - 32) * 4];
            v = *(const float4*)src;
        }
        bf16x4 bv = {(__bf16)v.x, (__bf16)v.y, (__bf16)v.z, (__bf16)v.w};
        *(bf16x4*)&zs[node * ZS + ch * 4] = bv;
    }
    __syncthreads();

    const bf16x8* w1v = (const bf16x8*)pwn1;
    const bf16x8* w2v = (const bf16x8*)pwn2;
    f32x4 a1[2][2];
    #pragma unroll
    for (int m = 0; m < 2; m++)
        #pragma unroll
        for (int n = 0; n < 2; n++) a1[m][n] = (f32x4){0,0,0,0};
    for (int kt = 0; kt < 8; kt++) {
        bf16x8 x[2];
        #pragma unroll
        for (int m = 0; m < 2; m++)
            x[m] = *(const bf16x8*)&zs[(m * 16 + c) * ZS + kt * 32 + quad * 8];
        #pragma unroll
        for (int n = 0; n < 2; n++) {
            bf16x8 w = w1v[((2 * wave + n) * 8 + kt) * 64 + lane];
            #pragma unroll
            for (int m = 0; m < 2; m++)
                a1[m][n] = __builtin_amdgcn_mfma_f32_16x16x32_bf16(w, x[m], a1[m][n], 0, 0, 0);
        }
    }
    __syncthreads();
    #pragma unroll
    for (int n = 0; n < 2; n++) {
        int nt = 2 * wave + n;
        float4 bb = *(const float4*)&bn1[nt * 16 + quad * 4];
        #pragma unroll
        for (int m = 0; m < 2; m++) {
            bf16x4 o = { (__bf16)fmaxf(a1[m][n][0] + bb.x, 0.f),
                         (__bf16)fmaxf(a1[m][n][1] + bb.y, 0.f),
                         (__bf16)fmaxf(a1[m][n][2] + bb.z, 0.f),
                         (__bf16)fmaxf(a1[m][n][3] + bb.w, 0.f) };
            *(bf16x4*)&h1s[(m * 16 + c) * HS + nt * 16 + quad * 4] = o;
        }
    }
    __syncthreads();

    f32x4 a2[2][2];
    #pragma unroll
    for (int m = 0; m < 2; m++)
        #pragma unroll
        for (int n = 0; n < 2; n++) a2[m][n] = (f32x4){0,0,0,0};
    for (int kt = 0; kt < 4; kt++) {
        bf16x8 x[2];
        #pragma unroll
        for (int m = 0; m < 2; m++)
            x[m] = *(const bf16x8*)&h1s[(m * 16 + c) * HS + kt * 32 + quad * 8];
        #pragma unroll
        for (int n = 0; n < 2; n++) {
            bf16x8 w = w2v[((2 * wave + n) * 4 + kt) * 64 + lane];
            #pragma unroll
            for (int m = 0; m < 2; m++)
                a2[m][n] = __builtin_amdgcn_mfma_f32_16x16x32_bf16(w, x[m], a2[m][n], 0, 0, 0);
        }
    }
    float* os = (float*)zs;   // stride 132 floats
    #pragma unroll
    for (int n = 0; n < 2; n++) {
        int nt = 2 * wave + n;
        float4 bb = *(const float4*)&bn2[nt * 16 + quad * 4];
        #pragma unroll
        for (int m = 0; m < 2; m++) {
            f32x4 o = { a2[m][n][0] + bb.x, a2[m][n][1] + bb.y,
                        a2[m][n][2] + bb.z, a2[m][n][3] + bb.w };
            *(f32x4*)&os[(m * 16 + c) * 132 + nt * 16 + quad * 4] = o;
        }
    }
    __syncthreads();

    #pragma unroll
    for (int it = 0; it < 4; it++) {
        int idx = it * 256 + t;              // 0..1023
        int node = idx >> 5, ch = idx & 31;
        int gn = n0 + node;
        if (gn < NN_) {
            size_t gb = ((size_t)b * NN_ + gn) * F + ch * 4;
            float4 hres = *(const float4*)&h[gb];
            float4 acc = *(const float4*)&os[node * 132 + ch * 4];
            float4 o = { hres.x + acc.x, hres.y + acc.y, hres.z + acc.z, hres.w + acc.w };
            *(float4*)&out_h[gb] = o;
        }
    }
    for (int idx = t; idx < NPB2 * 12; idx += 256) {
        int node = idx / 12, j = idx % 12;
        int gn = n0 + node;
        if (gn < NN_) {
            float deg = (float)(csr_off[gn + 1] - csr_off[gn]);
            size_t ci = ((size_t)b * NN_ + gn) * 12 + j;
            out_c[ci] = coord[ci] + agg_c[ci] / fmaxf(deg, 1.0f);
        }
    }
}

extern "C" void kernel_launch(void* const* d_in, const int* in_sizes, int n_in,
                              void* d_out, int out_size, void* d_ws, size_t ws_size,
                              hipStream_t stream) {
    const float* h     = (const float*)d_in[0];
    const float* coord = (const float*)d_in[1];
    const int*   ei    = (const int*)d_in[2];
    const float* ea    = (const float*)d_in[3];
    const float* We1   = (const float*)d_in[4];
    const float* be1   = (const float*)d_in[5];
    const float* We2   = (const float*)d_in[6];
    const float* be2   = (const float*)d_in[7];
    const float* Wn1   = (const float*)d_in[8];
    const float* bn1   = (const float*)d_in[9];
    const float* Wn2   = (const float*)d_in[10];
    const float* bn2   = (const float*)d_in[11];
    const float* Wc1   = (const float*)d_in[12];
    const float* bc1   = (const float*)d_in[13];
    const float* Wc2   = (const float*)d_in[14];

    float* out_h = (float*)d_out;                       // [B,N,F]
    float* out_c = out_h + (size_t)B * NN_ * F;         // [B,N,4,3]

    unsigned char* base = (unsigned char*)d_ws;
    __bf16* pw1  = (__bf16*)base;             // 36864 bf16
    __bf16* pw2  = pw1 + 36864;               // 16384
    __bf16* pwc1 = pw2 + 16384;               // 16384
    __bf16* pwc2 = pwc1 + 16384;              // 2048
    __bf16* pwn1 = pwc2 + 2048;               // 32768
    __bf16* pwn2 = pwn1 + 32768;              // 16384  -> 120832 elems = 241664 B
    unsigned char* dyn = base + 241664;

    int* csr_cnt = (int*)(dyn);               // 20000 B
    int* csr_off = (int*)(dyn + 20000);       // 20016 B
    int* csr_pos = (int*)(dyn + 40016);       // 20000 B
    int* bucket  = (int*)(dyn + 60016);       // 640000 B
    float* agg_h = (float*)(dyn + 700016);    // [B,N,HID]  5,120,000 B
    float* agg_c = agg_h + (size_t)B * NN_ * HID;            // [B,N,12] 480,000 B
    __bf16* pr   = (__bf16*)(agg_c + (size_t)B * NN_ * 12);  // 2,560,000 B
    __bf16* pc   = pr + (size_t)B * NN_ * F;                 // 2,560,000 B

    hipMemsetAsync(csr_cnt, 0, 20000, stream);

    // pack (236) | hist (313) | pr/pc GEMM (80) — GEMM overlaps hist
    pack_hist_kernel<<<629, 512, 0, stream>>>(We1, We2, Wc1, Wc2, Wn1, Wn2, ei, h, be1,
                                              pw1, pw2, pwc1, pwc2, pwn1, pwn2,
                                              (float4*)agg_h, csr_cnt, pr, pc);

    scan_kernel<<<1, 512, 0, stream>>>(csr_cnt, csr_off, csr_pos);

    scatter_kernel<<<313, 512, 0, stream>>>(ei, csr_pos, bucket);

    dim3 eg(NE_ / EDG, B);   // 2500 x 2
    edge_kernel<<<eg, 512, 0, stream>>>(pr, pc, coord, ei, ea, bucket, be2, bc1,
                                        pw1, pw2, pwc1, pwc2, agg_h, agg_c);

    dim3 ng((NN_ + NPB2 - 1) / NPB2, B);   // 157 x 2
    node_kernel<<<ng, 256, 0, stream>>>(h, agg_h, agg_c, coord, csr_off,
                                        pwn1, bn1, pwn2, bn2, out_h, out_c);
}